// Round 1
// baseline (3097.575 us; speedup 1.0000x reference)
//
#include <hip/hip_runtime.h>
#include <math.h>

#define NN 100000
#define NE 1600000
#define RR 5
#define HH 64
#define KK 10000
#define NTT 11
#define NBB 2
#define CW 320      // R*H relation columns
#define CALL 384    // + H root columns

// ---------------- h init: h[n] = emb[x[n]] ----------------
__global__ void k_init_h(const int* __restrict__ x, const float4* __restrict__ emb4,
                         float4* __restrict__ h4) {
    int idx = blockIdx.x * blockDim.x + threadIdx.x;
    if (idx >= NN * 16) return;
    int n = idx >> 4;
    int q = idx & 15;
    h4[idx] = emb4[x[n] * 16 + q];
}

// ---------------- PE add + absorbed mask ----------------
__global__ void k_pe(const int* __restrict__ order, float* __restrict__ h,
                     int* __restrict__ absorbed) {
    int idx = blockIdx.x * blockDim.x + threadIdx.x;
    if (idx >= KK * 16) return;
    int t = idx >> 4;
    int q = idx & 15;
    int node = order[t];
    float v = (float)sin((double)(t + 1));   // exact arg reduction, matches np
    float* p = h + (size_t)node * HH + q * 4;
    atomicAdd(p + 0, v);
    atomicAdd(p + 1, v);
    atomicAdd(p + 2, v);
    atomicAdd(p + 3, v);
    if (q == 0) absorbed[node] = 1;
}

// ---------------- per-(dst,rel) edge counts ----------------
__global__ void k_cnt(const int* __restrict__ dst, const int* __restrict__ et,
                      int* __restrict__ cnt) {
    int e = blockIdx.x * blockDim.x + threadIdx.x;
    if (e >= NE) return;
    atomicAdd(&cnt[dst[e] * RR + et[e]], 1);
}

// ---------------- build combined weight matrix Wall[c][k] ----------------
// c in [0,320): relation weights W_r = sum_b comp[r,b]*bases[b]; c = r*64+o, k = input dim
// c in [320,384): root[:, c-320]
__global__ void k_makeW01(const float* __restrict__ bases, const float* __restrict__ comp,
                          const float* __restrict__ root, float* __restrict__ Wall) {
    int idx = blockIdx.x * blockDim.x + threadIdx.x;
    if (idx >= CALL * HH) return;
    int c = idx >> 6, k = idx & 63;
    float w;
    if (c < CW) {
        int r = c >> 6, o = c & 63;
        w = comp[r * NBB + 0] * bases[k * HH + o] +
            comp[r * NBB + 1] * bases[HH * HH + k * HH + o];
    } else {
        w = root[k * HH + (c - CW)];
    }
    Wall[c * HH + k] = w;
}

// ---------------- GEMM: [N,64] x Wall^T -> xW [N,320] and hn = root part + bias ----------------
__launch_bounds__(256)
__global__ void k_gemm01(const float* __restrict__ h, const float* __restrict__ Wall,
                         const float* __restrict__ bias, float* __restrict__ xW,
                         float* __restrict__ hn) {
    __shared__ float hsT[64][68];  // [k][node]
    __shared__ float wsT[64][68];  // [k][col]
    int tid = threadIdx.x;
    int n0 = blockIdx.x * 64;
    int c0 = blockIdx.y * 64;

    for (int i = tid; i < 64 * 16; i += 256) {
        int row = i >> 4;
        int k4 = (i & 15) * 4;
        float4 v = make_float4(0.f, 0.f, 0.f, 0.f);
        int n = n0 + row;
        if (n < NN) v = *(const float4*)&h[(size_t)n * HH + k4];
        hsT[k4 + 0][row] = v.x; hsT[k4 + 1][row] = v.y;
        hsT[k4 + 2][row] = v.z; hsT[k4 + 3][row] = v.w;
        float4 wv = *(const float4*)&Wall[(c0 + row) * HH + k4];
        wsT[k4 + 0][row] = wv.x; wsT[k4 + 1][row] = wv.y;
        wsT[k4 + 2][row] = wv.z; wsT[k4 + 3][row] = wv.w;
    }
    __syncthreads();

    int tx = tid & 15, ty = tid >> 4;
    float acc[4][4];
#pragma unroll
    for (int i = 0; i < 4; i++)
#pragma unroll
        for (int j = 0; j < 4; j++) acc[i][j] = 0.f;

#pragma unroll
    for (int k = 0; k < 64; ++k) {
        float4 a4 = *(const float4*)&hsT[k][ty * 4];
        float4 b4 = *(const float4*)&wsT[k][tx * 4];
        float a[4] = {a4.x, a4.y, a4.z, a4.w};
        float b[4] = {b4.x, b4.y, b4.z, b4.w};
#pragma unroll
        for (int i = 0; i < 4; i++)
#pragma unroll
            for (int j = 0; j < 4; j++) acc[i][j] += a[i] * b[j];
    }

    if (c0 < CW) {
#pragma unroll
        for (int i = 0; i < 4; i++) {
            int n = n0 + ty * 4 + i;
            if (n >= NN) continue;
            float4 o4 = make_float4(acc[i][0], acc[i][1], acc[i][2], acc[i][3]);
            *(float4*)&xW[(size_t)n * CW + c0 + tx * 4] = o4;
        }
    } else {
        int ob = c0 - CW + tx * 4;
        float4 bv = *(const float4*)&bias[ob];
#pragma unroll
        for (int i = 0; i < 4; i++) {
            int n = n0 + ty * 4 + i;
            if (n >= NN) continue;
            float4 o4 = make_float4(acc[i][0] + bv.x, acc[i][1] + bv.y,
                                    acc[i][2] + bv.z, acc[i][3] + bv.w);
            *(float4*)&hn[(size_t)n * HH + ob] = o4;
        }
    }
}

// ---------------- layer-2 weights (out=1) ----------------
__global__ void k_makeW2(const float* __restrict__ bases2, const float* __restrict__ comp2,
                         const float* __restrict__ root2, float* __restrict__ W2) {
    int idx = blockIdx.x * blockDim.x + threadIdx.x;
    if (idx >= 6 * HH) return;
    int c = idx >> 6, k = idx & 63;
    float w = (c < RR) ? (comp2[c * NBB + 0] * bases2[k] + comp2[c * NBB + 1] * bases2[HH + k])
                       : root2[k];
    W2[c * HH + k] = w;
}

// ---------------- layer-2 GEMV: xW2[n][r], h2 = root part + bias ----------------
__global__ void k_gemm2(const float* __restrict__ h, const float* __restrict__ W2,
                        const float* __restrict__ bias2, float* __restrict__ xW2,
                        float* __restrict__ h2) {
    int n = blockIdx.x * blockDim.x + threadIdx.x;
    if (n >= NN) return;
    float hr[64];
#pragma unroll
    for (int q = 0; q < 16; q++) {
        float4 v = *(const float4*)&h[(size_t)n * HH + q * 4];
        hr[q * 4 + 0] = v.x; hr[q * 4 + 1] = v.y; hr[q * 4 + 2] = v.z; hr[q * 4 + 3] = v.w;
    }
#pragma unroll
    for (int c = 0; c < 6; c++) {
        float acc = 0.f;
#pragma unroll
        for (int k = 0; k < 64; k++) acc += hr[k] * W2[c * HH + k];
        if (c < RR) xW2[n * RR + c] = acc;
        else        h2[n] = acc + bias2[0];
    }
}

// ---------------- edge scatter (layers 0/1) ----------------
__global__ void k_scatter01(const int* __restrict__ src, const int* __restrict__ dst,
                            const int* __restrict__ et, const int* __restrict__ cnt,
                            const float* __restrict__ xW, float* __restrict__ hn) {
    int idx = blockIdx.x * blockDim.x + threadIdx.x;
    int e = idx >> 4;
    int q = idx & 15;
    if (e >= NE) return;
    int d = dst[e], r = et[e], s = src[e];
    int c = cnt[d * RR + r];
    float norm = 1.0f / (float)(c > 1 ? c : 1);
    float4 m = *(const float4*)&xW[((size_t)s * RR + r) * HH + q * 4];
    float* p = &hn[(size_t)d * HH + q * 4];
    atomicAdd(p + 0, m.x * norm);
    atomicAdd(p + 1, m.y * norm);
    atomicAdd(p + 2, m.z * norm);
    atomicAdd(p + 3, m.w * norm);
}

// ---------------- edge scatter (layer 2, scalar) ----------------
__global__ void k_scatter2(const int* __restrict__ src, const int* __restrict__ dst,
                           const int* __restrict__ et, const int* __restrict__ cnt,
                           const float* __restrict__ xW2, float* __restrict__ h2) {
    int e = blockIdx.x * blockDim.x + threadIdx.x;
    if (e >= NE) return;
    int d = dst[e], r = et[e], s = src[e];
    int c = cnt[d * RR + r];
    float norm = 1.0f / (float)(c > 1 ? c : 1);
    atomicAdd(&h2[d], xW2[s * RR + r] * norm);
}

// ---------------- masked exp-sum ----------------
__global__ void k_reduce(const float* __restrict__ h2, const int* __restrict__ absorbed,
                         float* __restrict__ denom) {
    __shared__ float sdata[256];
    int tid = threadIdx.x;
    float local = 0.f;
    for (int n = blockIdx.x * 256 + tid; n < NN; n += gridDim.x * 256)
        if (!absorbed[n]) local += expf(h2[n]);
    sdata[tid] = local;
    __syncthreads();
    for (int s = 128; s > 0; s >>= 1) {
        if (tid < s) sdata[tid] += sdata[tid + s];
        __syncthreads();
    }
    if (tid == 0) atomicAdd(denom, sdata[0]);
}

// ---------------- final normalize ----------------
__global__ void k_final(const float* __restrict__ h2, const int* __restrict__ absorbed,
                        const float* __restrict__ denom, float* __restrict__ out) {
    int n = blockIdx.x * blockDim.x + threadIdx.x;
    if (n >= NN) return;
    out[n] = absorbed[n] ? 0.f : expf(h2[n]) / denom[0];
}

extern "C" void kernel_launch(void* const* d_in, const int* in_sizes, int n_in,
                              void* d_out, int out_size, void* d_ws, size_t ws_size,
                              hipStream_t stream) {
    const int* x     = (const int*)d_in[0];
    const int* ei    = (const int*)d_in[1];
    const int* et    = (const int*)d_in[2];
    const int* order = (const int*)d_in[3];
    const float* emb = (const float*)d_in[4];
    const float* bases[3] = {(const float*)d_in[5], (const float*)d_in[9],  (const float*)d_in[13]};
    const float* comp[3]  = {(const float*)d_in[6], (const float*)d_in[10], (const float*)d_in[14]};
    const float* root[3]  = {(const float*)d_in[7], (const float*)d_in[11], (const float*)d_in[15]};
    const float* bias[3]  = {(const float*)d_in[8], (const float*)d_in[12], (const float*)d_in[16]};
    const int* srcp = ei;
    const int* dstp = ei + NE;

    char* w = (char*)d_ws;
    size_t off = 0;
    auto alloc = [&](size_t bytes) -> void* {
        void* p = w + off;
        off = (off + bytes + 255) & ~(size_t)255;
        return p;
    };
    float* h        = (float*)alloc((size_t)NN * HH * 4);
    float* hn       = (float*)alloc((size_t)NN * HH * 4);
    float* xW       = (float*)alloc((size_t)NN * CW * 4);
    float* xW2      = (float*)alloc((size_t)NN * RR * 4);
    float* h2       = (float*)alloc((size_t)NN * 4);
    int*   cnt      = (int*)alloc((size_t)NN * RR * 4);
    int*   absorbed = (int*)alloc((size_t)NN * 4);
    float* Wall     = (float*)alloc((size_t)CALL * HH * 4);
    float* W2       = (float*)alloc((size_t)6 * HH * 4);
    float* denom    = (float*)alloc(256);

    hipMemsetAsync(cnt, 0, (size_t)NN * RR * 4, stream);
    hipMemsetAsync(absorbed, 0, (size_t)NN * 4, stream);
    hipMemsetAsync(denom, 0, 4, stream);

    k_init_h<<<(NN * 16 + 255) / 256, 256, 0, stream>>>(x, (const float4*)emb, (float4*)h);
    k_pe<<<(KK * 16 + 255) / 256, 256, 0, stream>>>(order, h, absorbed);
    k_cnt<<<(NE + 255) / 256, 256, 0, stream>>>(dstp, et, cnt);

    dim3 gg((NN + 63) / 64, 6);

    // layer 0: h -> hn
    k_makeW01<<<(CALL * HH + 255) / 256, 256, 0, stream>>>(bases[0], comp[0], root[0], Wall);
    k_gemm01<<<gg, 256, 0, stream>>>(h, Wall, bias[0], xW, hn);
    k_scatter01<<<(NE * 16) / 256, 256, 0, stream>>>(srcp, dstp, et, cnt, xW, hn);

    // layer 1: hn -> h
    k_makeW01<<<(CALL * HH + 255) / 256, 256, 0, stream>>>(bases[1], comp[1], root[1], Wall);
    k_gemm01<<<gg, 256, 0, stream>>>(hn, Wall, bias[1], xW, h);
    k_scatter01<<<(NE * 16) / 256, 256, 0, stream>>>(srcp, dstp, et, cnt, xW, h);

    // layer 2: h -> h2
    k_makeW2<<<2, 256, 0, stream>>>(bases[2], comp[2], root[2], W2);
    k_gemm2<<<(NN + 255) / 256, 256, 0, stream>>>(h, W2, bias[2], xW2, h2);
    k_scatter2<<<(NE + 255) / 256, 256, 0, stream>>>(srcp, dstp, et, cnt, xW2, h2);

    k_reduce<<<256, 256, 0, stream>>>(h2, absorbed, denom);
    k_final<<<(NN + 255) / 256, 256, 0, stream>>>(h2, absorbed, denom, (float*)d_out);
}

// Round 2
// 685.363 us; speedup vs baseline: 4.5196x; 4.5196x over previous
//
#include <hip/hip_runtime.h>
#include <math.h>

#define NN 100000
#define NE 1600000
#define RR 5
#define HH 64
#define KK 10000
#define NTT 11
#define NBB 2
#define CW 320      // R*H relation columns
#define CALL 384    // + H root columns
#define NBLK ((NN + 255) / 256)   // scan blocks = 391

// ---------------- h init: h[n] = emb[x[n]] ----------------
__global__ void k_init_h(const int* __restrict__ x, const float4* __restrict__ emb4,
                         float4* __restrict__ h4) {
    int idx = blockIdx.x * blockDim.x + threadIdx.x;
    if (idx >= NN * 16) return;
    int n = idx >> 4;
    int q = idx & 15;
    h4[idx] = emb4[x[n] * 16 + q];
}

// ---------------- PE add + absorbed mask (node_order entries distinct) ----------------
__global__ void k_pe(const int* __restrict__ order, float* __restrict__ h,
                     int* __restrict__ absorbed) {
    int idx = blockIdx.x * blockDim.x + threadIdx.x;
    if (idx >= KK * 16) return;
    int t = idx >> 4;
    int q = idx & 15;
    int node = order[t];
    float v = (float)sin((double)(t + 1));   // exact arg reduction, matches np
    float* p = h + (size_t)node * HH + q * 4;
    p[0] += v; p[1] += v; p[2] += v; p[3] += v;
    if (q == 0) absorbed[node] = 1;
}

// ---------------- per-(dst,rel) edge counts ----------------
__global__ void k_cnt(const int* __restrict__ dst, const int* __restrict__ et,
                      int* __restrict__ cnt) {
    int e = blockIdx.x * blockDim.x + threadIdx.x;
    if (e >= NE) return;
    atomicAdd(&cnt[dst[e] * RR + et[e]], 1);
}

// ---------------- CSR build: scan over node degrees ----------------
__global__ void k_scan1(const int* __restrict__ cnt, int* __restrict__ rowstart,
                        int* __restrict__ bsum) {
    __shared__ int s[256];
    int tid = threadIdx.x;
    int d = blockIdx.x * 256 + tid;
    int deg = 0;
    if (d < NN) {
#pragma unroll
        for (int r = 0; r < RR; r++) deg += cnt[d * RR + r];
    }
    s[tid] = deg;
    __syncthreads();
#pragma unroll
    for (int off = 1; off < 256; off <<= 1) {
        int t = (tid >= off) ? s[tid - off] : 0;
        __syncthreads();
        s[tid] += t;
        __syncthreads();
    }
    if (d < NN) rowstart[d] = s[tid] - deg;   // exclusive within block
    if (tid == 255) bsum[blockIdx.x] = s[255];
}

__global__ void k_scan2(int* __restrict__ bsum) {
    __shared__ int s[512];
    int tid = threadIdx.x;
    int v = (tid < NBLK) ? bsum[tid] : 0;
    s[tid] = v;
    __syncthreads();
#pragma unroll
    for (int off = 1; off < 512; off <<= 1) {
        int t = (tid >= off) ? s[tid - off] : 0;
        __syncthreads();
        s[tid] += t;
        __syncthreads();
    }
    if (tid < NBLK) bsum[tid] = s[tid] - v;   // exclusive block offsets
}

__global__ void k_scan3(int* __restrict__ rowstart, const int* __restrict__ bsum) {
    int d = blockIdx.x * 256 + threadIdx.x;
    if (d < NN) rowstart[d] += bsum[blockIdx.x];
    if (d == 0) rowstart[NN] = NE;
}

// ---------------- edge placement into CSR ----------------
// epair[pos] = { src*8 + rel, bitcast(norm) }
__global__ void k_place(const int* __restrict__ src, const int* __restrict__ dst,
                        const int* __restrict__ et, const int* __restrict__ cnt,
                        const int* __restrict__ rowstart, int* __restrict__ cursor,
                        int2* __restrict__ epair) {
    int e = blockIdx.x * blockDim.x + threadIdx.x;
    if (e >= NE) return;
    int d = dst[e], r = et[e], s = src[e];
    int c = cnt[d * RR + r];
    float norm = 1.0f / (float)(c > 1 ? c : 1);
    int pos = rowstart[d] + atomicAdd(&cursor[d], 1);
    epair[pos] = make_int2((s << 3) | r, __float_as_int(norm));
}

// ---------------- build combined weight matrix Wall[c][k] ----------------
__global__ void k_makeW01(const float* __restrict__ bases, const float* __restrict__ comp,
                          const float* __restrict__ root, float* __restrict__ Wall) {
    int idx = blockIdx.x * blockDim.x + threadIdx.x;
    if (idx >= CALL * HH) return;
    int c = idx >> 6, k = idx & 63;
    float w;
    if (c < CW) {
        int r = c >> 6, o = c & 63;
        w = comp[r * NBB + 0] * bases[k * HH + o] +
            comp[r * NBB + 1] * bases[HH * HH + k * HH + o];
    } else {
        w = root[k * HH + (c - CW)];
    }
    Wall[c * HH + k] = w;
}

// ---------------- GEMM: [N,64] x Wall^T -> xW [N,320] and hn = root part + bias ----------------
__launch_bounds__(256)
__global__ void k_gemm01(const float* __restrict__ h, const float* __restrict__ Wall,
                         const float* __restrict__ bias, float* __restrict__ xW,
                         float* __restrict__ hn) {
    __shared__ float hsT[64][68];  // [k][node]
    __shared__ float wsT[64][68];  // [k][col]
    int tid = threadIdx.x;
    int n0 = blockIdx.x * 64;
    int c0 = blockIdx.y * 64;

    for (int i = tid; i < 64 * 16; i += 256) {
        int row = i >> 4;
        int k4 = (i & 15) * 4;
        float4 v = make_float4(0.f, 0.f, 0.f, 0.f);
        int n = n0 + row;
        if (n < NN) v = *(const float4*)&h[(size_t)n * HH + k4];
        hsT[k4 + 0][row] = v.x; hsT[k4 + 1][row] = v.y;
        hsT[k4 + 2][row] = v.z; hsT[k4 + 3][row] = v.w;
        float4 wv = *(const float4*)&Wall[(c0 + row) * HH + k4];
        wsT[k4 + 0][row] = wv.x; wsT[k4 + 1][row] = wv.y;
        wsT[k4 + 2][row] = wv.z; wsT[k4 + 3][row] = wv.w;
    }
    __syncthreads();

    int tx = tid & 15, ty = tid >> 4;
    float acc[4][4];
#pragma unroll
    for (int i = 0; i < 4; i++)
#pragma unroll
        for (int j = 0; j < 4; j++) acc[i][j] = 0.f;

#pragma unroll
    for (int k = 0; k < 64; ++k) {
        float4 a4 = *(const float4*)&hsT[k][ty * 4];
        float4 b4 = *(const float4*)&wsT[k][tx * 4];
        float a[4] = {a4.x, a4.y, a4.z, a4.w};
        float b[4] = {b4.x, b4.y, b4.z, b4.w};
#pragma unroll
        for (int i = 0; i < 4; i++)
#pragma unroll
            for (int j = 0; j < 4; j++) acc[i][j] += a[i] * b[j];
    }

    if (c0 < CW) {
#pragma unroll
        for (int i = 0; i < 4; i++) {
            int n = n0 + ty * 4 + i;
            if (n >= NN) continue;
            float4 o4 = make_float4(acc[i][0], acc[i][1], acc[i][2], acc[i][3]);
            *(float4*)&xW[(size_t)n * CW + c0 + tx * 4] = o4;
        }
    } else {
        int ob = c0 - CW + tx * 4;
        float4 bv = *(const float4*)&bias[ob];
#pragma unroll
        for (int i = 0; i < 4; i++) {
            int n = n0 + ty * 4 + i;
            if (n >= NN) continue;
            float4 o4 = make_float4(acc[i][0] + bv.x, acc[i][1] + bv.y,
                                    acc[i][2] + bv.z, acc[i][3] + bv.w);
            *(float4*)&hn[(size_t)n * HH + ob] = o4;
        }
    }
}

// ---------------- gather aggregation (layers 0/1): wave per dst, lane per dim ----------------
__launch_bounds__(256)
__global__ void k_gather01(const int* __restrict__ rowstart, const int2* __restrict__ epair,
                           const float* __restrict__ xW, float* __restrict__ hn) {
    int wid = (blockIdx.x * blockDim.x + threadIdx.x) >> 6;
    int lane = threadIdx.x & 63;
    if (wid >= NN) return;
    int beg = rowstart[wid], end = rowstart[wid + 1];
    float acc = 0.f;
    for (int j = beg; j < end; ++j) {
        int2 p = epair[j];                       // uniform across wave -> broadcast
        float w = __int_as_float(p.y);
        int sr = p.x;                            // src*8 + r
        acc += w * xW[((size_t)(sr >> 3) * RR + (sr & 7)) * HH + lane];
    }
    hn[(size_t)wid * HH + lane] += acc;
}

// ---------------- layer-2 weights (out=1) ----------------
__global__ void k_makeW2(const float* __restrict__ bases2, const float* __restrict__ comp2,
                         const float* __restrict__ root2, float* __restrict__ W2) {
    int idx = blockIdx.x * blockDim.x + threadIdx.x;
    if (idx >= 6 * HH) return;
    int c = idx >> 6, k = idx & 63;
    float w = (c < RR) ? (comp2[c * NBB + 0] * bases2[k] + comp2[c * NBB + 1] * bases2[HH + k])
                       : root2[k];
    W2[c * HH + k] = w;
}

// ---------------- layer-2 GEMV: xW2[n][r], h2 = root part + bias ----------------
__global__ void k_gemm2(const float* __restrict__ h, const float* __restrict__ W2,
                        const float* __restrict__ bias2, float* __restrict__ xW2,
                        float* __restrict__ h2) {
    int n = blockIdx.x * blockDim.x + threadIdx.x;
    if (n >= NN) return;
    float hr[64];
#pragma unroll
    for (int q = 0; q < 16; q++) {
        float4 v = *(const float4*)&h[(size_t)n * HH + q * 4];
        hr[q * 4 + 0] = v.x; hr[q * 4 + 1] = v.y; hr[q * 4 + 2] = v.z; hr[q * 4 + 3] = v.w;
    }
#pragma unroll
    for (int c = 0; c < 6; c++) {
        float acc = 0.f;
#pragma unroll
        for (int k = 0; k < 64; k++) acc += hr[k] * W2[c * HH + k];
        if (c < RR) xW2[n * RR + c] = acc;
        else        h2[n] = acc + bias2[0];
    }
}

// ---------------- layer-2 gather: thread per dst ----------------
__global__ void k_gather2(const int* __restrict__ rowstart, const int2* __restrict__ epair,
                          const float* __restrict__ xW2, float* __restrict__ h2) {
    int n = blockIdx.x * blockDim.x + threadIdx.x;
    if (n >= NN) return;
    int beg = rowstart[n], end = rowstart[n + 1];
    float acc = h2[n];
    for (int j = beg; j < end; ++j) {
        int2 p = epair[j];
        acc += __int_as_float(p.y) * xW2[(p.x >> 3) * RR + (p.x & 7)];
    }
    h2[n] = acc;
}

// ---------------- masked exp-sum ----------------
__global__ void k_reduce(const float* __restrict__ h2, const int* __restrict__ absorbed,
                         float* __restrict__ denom) {
    __shared__ float sdata[256];
    int tid = threadIdx.x;
    float local = 0.f;
    for (int n = blockIdx.x * 256 + tid; n < NN; n += gridDim.x * 256)
        if (!absorbed[n]) local += expf(h2[n]);
    sdata[tid] = local;
    __syncthreads();
    for (int s = 128; s > 0; s >>= 1) {
        if (tid < s) sdata[tid] += sdata[tid + s];
        __syncthreads();
    }
    if (tid == 0) atomicAdd(denom, sdata[0]);
}

// ---------------- final normalize ----------------
__global__ void k_final(const float* __restrict__ h2, const int* __restrict__ absorbed,
                        const float* __restrict__ denom, float* __restrict__ out) {
    int n = blockIdx.x * blockDim.x + threadIdx.x;
    if (n >= NN) return;
    out[n] = absorbed[n] ? 0.f : expf(h2[n]) / denom[0];
}

extern "C" void kernel_launch(void* const* d_in, const int* in_sizes, int n_in,
                              void* d_out, int out_size, void* d_ws, size_t ws_size,
                              hipStream_t stream) {
    const int* x     = (const int*)d_in[0];
    const int* ei    = (const int*)d_in[1];
    const int* et    = (const int*)d_in[2];
    const int* order = (const int*)d_in[3];
    const float* emb = (const float*)d_in[4];
    const float* bases[3] = {(const float*)d_in[5], (const float*)d_in[9],  (const float*)d_in[13]};
    const float* comp[3]  = {(const float*)d_in[6], (const float*)d_in[10], (const float*)d_in[14]};
    const float* root[3]  = {(const float*)d_in[7], (const float*)d_in[11], (const float*)d_in[15]};
    const float* bias[3]  = {(const float*)d_in[8], (const float*)d_in[12], (const float*)d_in[16]};
    const int* srcp = ei;
    const int* dstp = ei + NE;

    char* w = (char*)d_ws;
    size_t off = 0;
    auto alloc = [&](size_t bytes) -> void* {
        void* p = w + off;
        off = (off + bytes + 255) & ~(size_t)255;
        return p;
    };
    float* h        = (float*)alloc((size_t)NN * HH * 4);
    float* hn       = (float*)alloc((size_t)NN * HH * 4);
    float* xW       = (float*)alloc((size_t)NN * CW * 4);
    float* xW2      = (float*)alloc((size_t)NN * RR * 4);
    float* h2       = (float*)alloc((size_t)NN * 4);
    int*   cnt      = (int*)alloc((size_t)NN * RR * 4);
    int*   absorbed = (int*)alloc((size_t)NN * 4);
    int*   rowstart = (int*)alloc((size_t)(NN + 1) * 4);
    int*   cursor   = (int*)alloc((size_t)NN * 4);
    int*   bsum     = (int*)alloc((size_t)NBLK * 4);
    int2*  epair    = (int2*)alloc((size_t)NE * 8);
    float* Wall     = (float*)alloc((size_t)CALL * HH * 4);
    float* W2       = (float*)alloc((size_t)6 * HH * 4);
    float* denom    = (float*)alloc(256);

    hipMemsetAsync(cnt, 0, (size_t)NN * RR * 4, stream);
    hipMemsetAsync(cursor, 0, (size_t)NN * 4, stream);
    hipMemsetAsync(absorbed, 0, (size_t)NN * 4, stream);
    hipMemsetAsync(denom, 0, 4, stream);

    k_init_h<<<(NN * 16 + 255) / 256, 256, 0, stream>>>(x, (const float4*)emb, (float4*)h);
    k_pe<<<(KK * 16 + 255) / 256, 256, 0, stream>>>(order, h, absorbed);
    k_cnt<<<(NE + 255) / 256, 256, 0, stream>>>(dstp, et, cnt);

    // CSR build
    k_scan1<<<NBLK, 256, 0, stream>>>(cnt, rowstart, bsum);
    k_scan2<<<1, 512, 0, stream>>>(bsum);
    k_scan3<<<NBLK, 256, 0, stream>>>(rowstart, bsum);
    k_place<<<(NE + 255) / 256, 256, 0, stream>>>(srcp, dstp, et, cnt, rowstart, cursor, epair);

    dim3 gg((NN + 63) / 64, 6);

    // layer 0: h -> hn
    k_makeW01<<<(CALL * HH + 255) / 256, 256, 0, stream>>>(bases[0], comp[0], root[0], Wall);
    k_gemm01<<<gg, 256, 0, stream>>>(h, Wall, bias[0], xW, hn);
    k_gather01<<<(NN * 64 + 255) / 256, 256, 0, stream>>>(rowstart, epair, xW, hn);

    // layer 1: hn -> h
    k_makeW01<<<(CALL * HH + 255) / 256, 256, 0, stream>>>(bases[1], comp[1], root[1], Wall);
    k_gemm01<<<gg, 256, 0, stream>>>(hn, Wall, bias[1], xW, h);
    k_gather01<<<(NN * 64 + 255) / 256, 256, 0, stream>>>(rowstart, epair, xW, h);

    // layer 2: h -> h2
    k_makeW2<<<2, 256, 0, stream>>>(bases[2], comp[2], root[2], W2);
    k_gemm2<<<(NN + 255) / 256, 256, 0, stream>>>(h, W2, bias[2], xW2, h2);
    k_gather2<<<(NN + 255) / 256, 256, 0, stream>>>(rowstart, epair, xW2, h2);

    k_reduce<<<256, 256, 0, stream>>>(h2, absorbed, denom);
    k_final<<<(NN + 255) / 256, 256, 0, stream>>>(h2, absorbed, denom, (float*)d_out);
}

// Round 3
// 510.925 us; speedup vs baseline: 6.0627x; 1.3414x over previous
//
#include <hip/hip_runtime.h>
#include <math.h>

#define NN 100000
#define NE 1600000
#define RR 5
#define HH 64
#define KK 10000
#define NBB 2
#define NBLK ((NN + 255) / 256)   // scan blocks = 391

// ---------------- h init: h[n] = emb[x[n]] ----------------
__global__ void k_init_h(const int* __restrict__ x, const float4* __restrict__ emb4,
                         float4* __restrict__ h4) {
    int idx = blockIdx.x * blockDim.x + threadIdx.x;
    if (idx >= NN * 16) return;
    int n = idx >> 4;
    int q = idx & 15;
    h4[idx] = emb4[x[n] * 16 + q];
}

// ---------------- PE add + absorbed mask (node_order entries distinct) ----------------
__global__ void k_pe(const int* __restrict__ order, float* __restrict__ h,
                     int* __restrict__ absorbed) {
    int idx = blockIdx.x * blockDim.x + threadIdx.x;
    if (idx >= KK * 16) return;
    int t = idx >> 4;
    int q = idx & 15;
    int node = order[t];
    float v = (float)sin((double)(t + 1));   // exact arg reduction, matches np
    float* p = h + (size_t)node * HH + q * 4;
    p[0] += v; p[1] += v; p[2] += v; p[3] += v;
    if (q == 0) absorbed[node] = 1;
}

// ---------------- per-(dst,rel) edge counts ----------------
__global__ void k_cnt(const int* __restrict__ dst, const int* __restrict__ et,
                      int* __restrict__ cnt) {
    int e = blockIdx.x * blockDim.x + threadIdx.x;
    if (e >= NE) return;
    atomicAdd(&cnt[dst[e] * RR + et[e]], 1);
}

// ---------------- CSR build: scan over node degrees ----------------
__global__ void k_scan1(const int* __restrict__ cnt, int* __restrict__ rowstart,
                        int* __restrict__ bsum) {
    __shared__ int s[256];
    int tid = threadIdx.x;
    int d = blockIdx.x * 256 + tid;
    int deg = 0;
    if (d < NN) {
#pragma unroll
        for (int r = 0; r < RR; r++) deg += cnt[d * RR + r];
    }
    s[tid] = deg;
    __syncthreads();
#pragma unroll
    for (int off = 1; off < 256; off <<= 1) {
        int t = (tid >= off) ? s[tid - off] : 0;
        __syncthreads();
        s[tid] += t;
        __syncthreads();
    }
    if (d < NN) rowstart[d] = s[tid] - deg;   // exclusive within block
    if (tid == 255) bsum[blockIdx.x] = s[255];
}

__global__ void k_scan2(int* __restrict__ bsum) {
    __shared__ int s[512];
    int tid = threadIdx.x;
    int v = (tid < NBLK) ? bsum[tid] : 0;
    s[tid] = v;
    __syncthreads();
#pragma unroll
    for (int off = 1; off < 512; off <<= 1) {
        int t = (tid >= off) ? s[tid - off] : 0;
        __syncthreads();
        s[tid] += t;
        __syncthreads();
    }
    if (tid < NBLK) bsum[tid] = s[tid] - v;   // exclusive block offsets
}

__global__ void k_scan3(int* __restrict__ rowstart, const int* __restrict__ bsum) {
    int d = blockIdx.x * 256 + threadIdx.x;
    if (d < NN) rowstart[d] += bsum[blockIdx.x];
    if (d == 0) rowstart[NN] = NE;
}

// ---------------- edge placement into CSR ----------------
// epair[pos] = { src*8 + rel, bitcast(norm) }
__global__ void k_place(const int* __restrict__ src, const int* __restrict__ dst,
                        const int* __restrict__ et, const int* __restrict__ cnt,
                        const int* __restrict__ rowstart, int* __restrict__ cursor,
                        int2* __restrict__ epair) {
    int e = blockIdx.x * blockDim.x + threadIdx.x;
    if (e >= NE) return;
    int d = dst[e], r = et[e], s = src[e];
    int c = cnt[d * RR + r];
    float norm = 1.0f / (float)(c > 1 ? c : 1);
    int pos = rowstart[d] + atomicAdd(&cursor[d], 1);
    epair[pos] = make_int2((s << 3) | r, __float_as_int(norm));
}

// ---------------- basis-mixed gather: wave per dst, lane per dim ----------------
// mix_b[dst, i] = sum_e comp[r_e, b] * norm_e * h[src_e, i]    (b = 0, 1)
__launch_bounds__(256)
__global__ void k_gather_mix(const int* __restrict__ rowstart, const int2* __restrict__ epair,
                             const float* __restrict__ comp, const float* __restrict__ h,
                             float* __restrict__ mixbuf) {
    __shared__ float2 lut[RR];
    if (threadIdx.x < RR)
        lut[threadIdx.x] = make_float2(comp[threadIdx.x * NBB + 0],
                                       comp[threadIdx.x * NBB + 1]);
    __syncthreads();
    int wid = (blockIdx.x * blockDim.x + threadIdx.x) >> 6;
    int lane = threadIdx.x & 63;
    if (wid >= NN) return;
    int beg = rowstart[wid], end = rowstart[wid + 1];
    float m0a = 0.f, m1a = 0.f, m0b = 0.f, m1b = 0.f;
    int j = beg;
    for (; j + 1 < end; j += 2) {
        int2 pa = epair[j];
        int2 pb = epair[j + 1];
        float ha = h[(size_t)(pa.x >> 3) * HH + lane];
        float hb = h[(size_t)(pb.x >> 3) * HH + lane];
        float2 ca = lut[pa.x & 7];
        float2 cb = lut[pb.x & 7];
        float na = __int_as_float(pa.y) * ha;
        float nb = __int_as_float(pb.y) * hb;
        m0a += ca.x * na;  m1a += ca.y * na;
        m0b += cb.x * nb;  m1b += cb.y * nb;
    }
    if (j < end) {
        int2 p = epair[j];
        float hv = h[(size_t)(p.x >> 3) * HH + lane];
        float2 c = lut[p.x & 7];
        float nh = __int_as_float(p.y) * hv;
        m0a += c.x * nh;  m1a += c.y * nh;
    }
    mixbuf[(size_t)wid * 128 + lane]      = m0a + m0b;
    mixbuf[(size_t)wid * 128 + 64 + lane] = m1a + m1b;
}

// ---------------- layer GEMM: hn = [mix0|mix1|h] (K=192) x [B0;B1;root] + bias ----------------
__launch_bounds__(256)
__global__ void k_gemmL(const float* __restrict__ mixbuf, const float* __restrict__ h,
                        const float* __restrict__ bases, const float* __restrict__ root,
                        const float* __restrict__ bias, float* __restrict__ hn) {
    __shared__ float hsT[64][68];  // [k][node]
    __shared__ float ws[64][68];   // [k][o]
    int tid = threadIdx.x;
    int n0 = blockIdx.x * 64;
    int tx = tid & 15, ty = tid >> 4;
    float acc[4][4];
#pragma unroll
    for (int i = 0; i < 4; i++)
#pragma unroll
        for (int j = 0; j < 4; j++) acc[i][j] = 0.f;

    for (int chunk = 0; chunk < 3; ++chunk) {
        __syncthreads();
        for (int i = tid; i < 64 * 16; i += 256) {
            int row = i >> 4;            // A: node idx | W: k idx
            int q4 = (i & 15) * 4;       // A: k offset | W: o offset
            int n = n0 + row;
            float4 v = make_float4(0.f, 0.f, 0.f, 0.f);
            if (n < NN) {
                const float* asrc = (chunk == 0) ? &mixbuf[(size_t)n * 128 + q4]
                                  : (chunk == 1) ? &mixbuf[(size_t)n * 128 + 64 + q4]
                                                 : &h[(size_t)n * HH + q4];
                v = *(const float4*)asrc;
            }
            hsT[q4 + 0][row] = v.x; hsT[q4 + 1][row] = v.y;
            hsT[q4 + 2][row] = v.z; hsT[q4 + 3][row] = v.w;

            const float* wsrc = (chunk == 0) ? &bases[(size_t)row * HH + q4]
                              : (chunk == 1) ? &bases[(size_t)(64 + row) * HH + q4]
                                             : &root[(size_t)row * HH + q4];
            *(float4*)&ws[row][q4] = *(const float4*)wsrc;
        }
        __syncthreads();

#pragma unroll
        for (int k = 0; k < 64; ++k) {
            float4 a4 = *(const float4*)&hsT[k][ty * 4];
            float4 b4 = *(const float4*)&ws[k][tx * 4];
            float a[4] = {a4.x, a4.y, a4.z, a4.w};
            float b[4] = {b4.x, b4.y, b4.z, b4.w};
#pragma unroll
            for (int i = 0; i < 4; i++)
#pragma unroll
                for (int j = 0; j < 4; j++) acc[i][j] += a[i] * b[j];
        }
    }

    float4 bv = *(const float4*)&bias[tx * 4];
#pragma unroll
    for (int i = 0; i < 4; i++) {
        int n = n0 + ty * 4 + i;
        if (n >= NN) continue;
        float4 o4 = make_float4(acc[i][0] + bv.x, acc[i][1] + bv.y,
                                acc[i][2] + bv.z, acc[i][3] + bv.w);
        *(float4*)&hn[(size_t)n * HH + tx * 4] = o4;
    }
}

// ---------------- layer-2 weights (out=1) ----------------
__global__ void k_makeW2(const float* __restrict__ bases2, const float* __restrict__ comp2,
                         const float* __restrict__ root2, float* __restrict__ W2) {
    int idx = blockIdx.x * blockDim.x + threadIdx.x;
    if (idx >= 6 * HH) return;
    int c = idx >> 6, k = idx & 63;
    float w = (c < RR) ? (comp2[c * NBB + 0] * bases2[k] + comp2[c * NBB + 1] * bases2[HH + k])
                       : root2[k];
    W2[c * HH + k] = w;
}

// ---------------- layer-2 GEMV: xW2[n][r], h2 = root part + bias ----------------
__global__ void k_gemm2(const float* __restrict__ h, const float* __restrict__ W2,
                        const float* __restrict__ bias2, float* __restrict__ xW2,
                        float* __restrict__ h2) {
    int n = blockIdx.x * blockDim.x + threadIdx.x;
    if (n >= NN) return;
    float hr[64];
#pragma unroll
    for (int q = 0; q < 16; q++) {
        float4 v = *(const float4*)&h[(size_t)n * HH + q * 4];
        hr[q * 4 + 0] = v.x; hr[q * 4 + 1] = v.y; hr[q * 4 + 2] = v.z; hr[q * 4 + 3] = v.w;
    }
#pragma unroll
    for (int c = 0; c < 6; c++) {
        float acc = 0.f;
#pragma unroll
        for (int k = 0; k < 64; k++) acc += hr[k] * W2[c * HH + k];
        if (c < RR) xW2[n * RR + c] = acc;
        else        h2[n] = acc + bias2[0];
    }
}

// ---------------- layer-2 gather: thread per dst ----------------
__global__ void k_gather2(const int* __restrict__ rowstart, const int2* __restrict__ epair,
                          const float* __restrict__ xW2, float* __restrict__ h2) {
    int n = blockIdx.x * blockDim.x + threadIdx.x;
    if (n >= NN) return;
    int beg = rowstart[n], end = rowstart[n + 1];
    float acc = h2[n];
    for (int j = beg; j < end; ++j) {
        int2 p = epair[j];
        acc += __int_as_float(p.y) * xW2[(p.x >> 3) * RR + (p.x & 7)];
    }
    h2[n] = acc;
}

// ---------------- masked exp-sum ----------------
__global__ void k_reduce(const float* __restrict__ h2, const int* __restrict__ absorbed,
                         float* __restrict__ denom) {
    __shared__ float sdata[256];
    int tid = threadIdx.x;
    float local = 0.f;
    for (int n = blockIdx.x * 256 + tid; n < NN; n += gridDim.x * 256)
        if (!absorbed[n]) local += expf(h2[n]);
    sdata[tid] = local;
    __syncthreads();
    for (int s = 128; s > 0; s >>= 1) {
        if (tid < s) sdata[tid] += sdata[tid + s];
        __syncthreads();
    }
    if (tid == 0) atomicAdd(denom, sdata[0]);
}

// ---------------- final normalize ----------------
__global__ void k_final(const float* __restrict__ h2, const int* __restrict__ absorbed,
                        const float* __restrict__ denom, float* __restrict__ out) {
    int n = blockIdx.x * blockDim.x + threadIdx.x;
    if (n >= NN) return;
    out[n] = absorbed[n] ? 0.f : expf(h2[n]) / denom[0];
}

extern "C" void kernel_launch(void* const* d_in, const int* in_sizes, int n_in,
                              void* d_out, int out_size, void* d_ws, size_t ws_size,
                              hipStream_t stream) {
    const int* x     = (const int*)d_in[0];
    const int* ei    = (const int*)d_in[1];
    const int* et    = (const int*)d_in[2];
    const int* order = (const int*)d_in[3];
    const float* emb = (const float*)d_in[4];
    const float* bases[3] = {(const float*)d_in[5], (const float*)d_in[9],  (const float*)d_in[13]};
    const float* comp[3]  = {(const float*)d_in[6], (const float*)d_in[10], (const float*)d_in[14]};
    const float* root[3]  = {(const float*)d_in[7], (const float*)d_in[11], (const float*)d_in[15]};
    const float* bias[3]  = {(const float*)d_in[8], (const float*)d_in[12], (const float*)d_in[16]};
    const int* srcp = ei;
    const int* dstp = ei + NE;

    char* w = (char*)d_ws;
    size_t off = 0;
    auto alloc = [&](size_t bytes) -> void* {
        void* p = w + off;
        off = (off + bytes + 255) & ~(size_t)255;
        return p;
    };
    float* h        = (float*)alloc((size_t)NN * HH * 4);
    float* hn       = (float*)alloc((size_t)NN * HH * 4);
    float* mixbuf   = (float*)alloc((size_t)NN * 128 * 4);
    float* xW2      = (float*)alloc((size_t)NN * RR * 4);
    float* h2       = (float*)alloc((size_t)NN * 4);
    int*   cnt      = (int*)alloc((size_t)NN * RR * 4);
    int*   absorbed = (int*)alloc((size_t)NN * 4);
    int*   rowstart = (int*)alloc((size_t)(NN + 1) * 4);
    int*   cursor   = (int*)alloc((size_t)NN * 4);
    int*   bsum     = (int*)alloc((size_t)NBLK * 4);
    int2*  epair    = (int2*)alloc((size_t)NE * 8);
    float* W2       = (float*)alloc((size_t)6 * HH * 4);
    float* denom    = (float*)alloc(256);

    hipMemsetAsync(cnt, 0, (size_t)NN * RR * 4, stream);
    hipMemsetAsync(cursor, 0, (size_t)NN * 4, stream);
    hipMemsetAsync(absorbed, 0, (size_t)NN * 4, stream);
    hipMemsetAsync(denom, 0, 4, stream);

    k_init_h<<<(NN * 16 + 255) / 256, 256, 0, stream>>>(x, (const float4*)emb, (float4*)h);
    k_pe<<<(KK * 16 + 255) / 256, 256, 0, stream>>>(order, h, absorbed);
    k_cnt<<<(NE + 255) / 256, 256, 0, stream>>>(dstp, et, cnt);

    // CSR build
    k_scan1<<<NBLK, 256, 0, stream>>>(cnt, rowstart, bsum);
    k_scan2<<<1, 512, 0, stream>>>(bsum);
    k_scan3<<<NBLK, 256, 0, stream>>>(rowstart, bsum);
    k_place<<<(NE + 255) / 256, 256, 0, stream>>>(srcp, dstp, et, cnt, rowstart, cursor, epair);

    int gmix = (NN * 64 + 255) / 256;
    int ggemm = (NN + 63) / 64;

    // layer 0: h -> hn
    k_gather_mix<<<gmix, 256, 0, stream>>>(rowstart, epair, comp[0], h, mixbuf);
    k_gemmL<<<ggemm, 256, 0, stream>>>(mixbuf, h, bases[0], root[0], bias[0], hn);

    // layer 1: hn -> h
    k_gather_mix<<<gmix, 256, 0, stream>>>(rowstart, epair, comp[1], hn, mixbuf);
    k_gemmL<<<ggemm, 256, 0, stream>>>(mixbuf, hn, bases[1], root[1], bias[1], h);

    // layer 2: h -> h2
    k_makeW2<<<2, 256, 0, stream>>>(bases[2], comp[2], root[2], W2);
    k_gemm2<<<(NN + 255) / 256, 256, 0, stream>>>(h, W2, bias[2], xW2, h2);
    k_gather2<<<(NN + 255) / 256, 256, 0, stream>>>(rowstart, epair, xW2, h2);

    k_reduce<<<256, 256, 0, stream>>>(h2, absorbed, denom);
    k_final<<<(NN + 255) / 256, 256, 0, stream>>>(h2, absorbed, denom, (float*)d_out);
}

// Round 4
// 432.971 us; speedup vs baseline: 7.1542x; 1.1800x over previous
//
#include <hip/hip_runtime.h>
#include <math.h>

#define NN 100000
#define NE 1600000
#define RR 5
#define HH 64
#define KK 10000
#define NBB 2
#define NBLK ((NN + 255) / 256)   // scan blocks = 391

// ---------------- h init: h[n] = emb[x[n]] ----------------
__global__ void k_init_h(const int* __restrict__ x, const float4* __restrict__ emb4,
                         float4* __restrict__ h4) {
    int idx = blockIdx.x * blockDim.x + threadIdx.x;
    if (idx >= NN * 16) return;
    int n = idx >> 4;
    int q = idx & 15;
    h4[idx] = emb4[x[n] * 16 + q];
}

// ---------------- PE add + absorbed mask (node_order entries distinct) ----------------
__global__ void k_pe(const int* __restrict__ order, float* __restrict__ h,
                     int* __restrict__ absorbed) {
    int idx = blockIdx.x * blockDim.x + threadIdx.x;
    if (idx >= KK * 16) return;
    int t = idx >> 4;
    int q = idx & 15;
    int node = order[t];
    float v = (float)sin((double)(t + 1));   // exact arg reduction, matches np
    float* p = h + (size_t)node * HH + q * 4;
    p[0] += v; p[1] += v; p[2] += v; p[3] += v;
    if (q == 0) absorbed[node] = 1;
}

// ---------------- per-(dst,rel) edge counts ----------------
__global__ void k_cnt(const int* __restrict__ dst, const int* __restrict__ et,
                      int* __restrict__ cnt) {
    int e = blockIdx.x * blockDim.x + threadIdx.x;
    if (e >= NE) return;
    atomicAdd(&cnt[dst[e] * RR + et[e]], 1);
}

// ---------------- CSR build: scan over node degrees ----------------
__global__ void k_scan1(const int* __restrict__ cnt, int* __restrict__ rowstart,
                        int* __restrict__ bsum) {
    __shared__ int s[256];
    int tid = threadIdx.x;
    int d = blockIdx.x * 256 + tid;
    int deg = 0;
    if (d < NN) {
#pragma unroll
        for (int r = 0; r < RR; r++) deg += cnt[d * RR + r];
    }
    s[tid] = deg;
    __syncthreads();
#pragma unroll
    for (int off = 1; off < 256; off <<= 1) {
        int t = (tid >= off) ? s[tid - off] : 0;
        __syncthreads();
        s[tid] += t;
        __syncthreads();
    }
    if (d < NN) rowstart[d] = s[tid] - deg;   // exclusive within block
    if (tid == 255) bsum[blockIdx.x] = s[255];
}

__global__ void k_scan2(int* __restrict__ bsum) {
    __shared__ int s[512];
    int tid = threadIdx.x;
    int v = (tid < NBLK) ? bsum[tid] : 0;
    s[tid] = v;
    __syncthreads();
#pragma unroll
    for (int off = 1; off < 512; off <<= 1) {
        int t = (tid >= off) ? s[tid - off] : 0;
        __syncthreads();
        s[tid] += t;
        __syncthreads();
    }
    if (tid < NBLK) bsum[tid] = s[tid] - v;   // exclusive block offsets
}

__global__ void k_scan3(int* __restrict__ rowstart, const int* __restrict__ bsum) {
    int d = blockIdx.x * 256 + threadIdx.x;
    if (d < NN) rowstart[d] += bsum[blockIdx.x];
    if (d == 0) rowstart[NN] = NE;
}

// ---------------- edge placement into CSR ----------------
// epair[pos] = { src*8 + rel, bitcast(norm) }
__global__ void k_place(const int* __restrict__ src, const int* __restrict__ dst,
                        const int* __restrict__ et, const int* __restrict__ cnt,
                        const int* __restrict__ rowstart, int* __restrict__ cursor,
                        int2* __restrict__ epair) {
    int e = blockIdx.x * blockDim.x + threadIdx.x;
    if (e >= NE) return;
    int d = dst[e], r = et[e], s = src[e];
    int c = cnt[d * RR + r];
    float norm = 1.0f / (float)(c > 1 ? c : 1);
    int pos = rowstart[d] + atomicAdd(&cursor[d], 1);
    epair[pos] = make_int2((s << 3) | r, __float_as_int(norm));
}

// ---------------- basis-mixed gather: wave per dst, 4 edge-groups x float4 lanes ----------------
// mix_b[dst, i] = sum_e comp[r_e, b] * norm_e * h[src_e, i]    (b = 0, 1)
__launch_bounds__(256)
__global__ void k_gather_mix(const int* __restrict__ rowstart, const int2* __restrict__ epair,
                             const float* __restrict__ comp, const float* __restrict__ h,
                             float* __restrict__ mixbuf) {
    __shared__ float2 lut[8];
    if (threadIdx.x < 8) {
        int r = threadIdx.x < RR ? threadIdx.x : 0;
        lut[threadIdx.x] = make_float2(comp[r * NBB + 0], comp[r * NBB + 1]);
    }
    __syncthreads();
    int wid = (blockIdx.x * blockDim.x + threadIdx.x) >> 6;
    if (wid >= NN) return;
    int lane = threadIdx.x & 63;
    int eg = lane >> 4;          // edge group 0..3
    int dq = lane & 15;          // dim quarter: dims [dq*4, dq*4+4)
    int beg = rowstart[wid], end = rowstart[wid + 1];

    float4 m0 = make_float4(0.f, 0.f, 0.f, 0.f);
    float4 m1 = make_float4(0.f, 0.f, 0.f, 0.f);

    for (int j = beg; j < end; j += 8) {
        int jj0 = j + eg;
        int jj1 = j + 4 + eg;
        int2 pa = (jj0 < end) ? epair[jj0] : make_int2(0, 0);
        int2 pb = (jj1 < end) ? epair[jj1] : make_int2(0, 0);
        float4 ha = *(const float4*)&h[(size_t)(pa.x >> 3) * HH + dq * 4];
        float4 hb = *(const float4*)&h[(size_t)(pb.x >> 3) * HH + dq * 4];
        float2 ca = lut[pa.x & 7];
        float2 cb = lut[pb.x & 7];
        float na = __int_as_float(pa.y);
        float nb = __int_as_float(pb.y);
        float a0 = ca.x * na, a1 = ca.y * na;
        float b0 = cb.x * nb, b1 = cb.y * nb;
        m0.x += a0 * ha.x; m0.y += a0 * ha.y; m0.z += a0 * ha.z; m0.w += a0 * ha.w;
        m1.x += a1 * ha.x; m1.y += a1 * ha.y; m1.z += a1 * ha.z; m1.w += a1 * ha.w;
        m0.x += b0 * hb.x; m0.y += b0 * hb.y; m0.z += b0 * hb.z; m0.w += b0 * hb.w;
        m1.x += b1 * hb.x; m1.y += b1 * hb.y; m1.z += b1 * hb.z; m1.w += b1 * hb.w;
    }

    // fold the 4 edge groups: butterfly over lane bits 4,5
#pragma unroll
    for (int off = 16; off < 64; off <<= 1) {
        m0.x += __shfl_xor(m0.x, off); m0.y += __shfl_xor(m0.y, off);
        m0.z += __shfl_xor(m0.z, off); m0.w += __shfl_xor(m0.w, off);
        m1.x += __shfl_xor(m1.x, off); m1.y += __shfl_xor(m1.y, off);
        m1.z += __shfl_xor(m1.z, off); m1.w += __shfl_xor(m1.w, off);
    }

    if (eg == 0)      *(float4*)&mixbuf[(size_t)wid * 128 + dq * 4]      = m0;
    else if (eg == 1) *(float4*)&mixbuf[(size_t)wid * 128 + 64 + dq * 4] = m1;
}

// ---------------- layer GEMM: hn = [mix0|mix1|h] (K=192) x [B0;B1;root] + bias ----------------
__launch_bounds__(256)
__global__ void k_gemmL(const float* __restrict__ mixbuf, const float* __restrict__ h,
                        const float* __restrict__ bases, const float* __restrict__ root,
                        const float* __restrict__ bias, float* __restrict__ hn) {
    __shared__ float hsT[64][68];  // [k][node]
    __shared__ float ws[64][68];   // [k][o]
    int tid = threadIdx.x;
    int n0 = blockIdx.x * 64;
    int tx = tid & 15, ty = tid >> 4;
    float acc[4][4];
#pragma unroll
    for (int i = 0; i < 4; i++)
#pragma unroll
        for (int j = 0; j < 4; j++) acc[i][j] = 0.f;

    for (int chunk = 0; chunk < 3; ++chunk) {
        __syncthreads();
        for (int i = tid; i < 64 * 16; i += 256) {
            int row = i >> 4;            // A: node idx | W: k idx
            int q4 = (i & 15) * 4;       // A: k offset | W: o offset
            int n = n0 + row;
            float4 v = make_float4(0.f, 0.f, 0.f, 0.f);
            if (n < NN) {
                const float* asrc = (chunk == 0) ? &mixbuf[(size_t)n * 128 + q4]
                                  : (chunk == 1) ? &mixbuf[(size_t)n * 128 + 64 + q4]
                                                 : &h[(size_t)n * HH + q4];
                v = *(const float4*)asrc;
            }
            hsT[q4 + 0][row] = v.x; hsT[q4 + 1][row] = v.y;
            hsT[q4 + 2][row] = v.z; hsT[q4 + 3][row] = v.w;

            const float* wsrc = (chunk == 0) ? &bases[(size_t)row * HH + q4]
                              : (chunk == 1) ? &bases[(size_t)(64 + row) * HH + q4]
                                             : &root[(size_t)row * HH + q4];
            *(float4*)&ws[row][q4] = *(const float4*)wsrc;
        }
        __syncthreads();

#pragma unroll
        for (int k = 0; k < 64; ++k) {
            float4 a4 = *(const float4*)&hsT[k][ty * 4];
            float4 b4 = *(const float4*)&ws[k][tx * 4];
            float a[4] = {a4.x, a4.y, a4.z, a4.w};
            float b[4] = {b4.x, b4.y, b4.z, b4.w};
#pragma unroll
            for (int i = 0; i < 4; i++)
#pragma unroll
                for (int j = 0; j < 4; j++) acc[i][j] += a[i] * b[j];
        }
    }

    float4 bv = *(const float4*)&bias[tx * 4];
#pragma unroll
    for (int i = 0; i < 4; i++) {
        int n = n0 + ty * 4 + i;
        if (n >= NN) continue;
        float4 o4 = make_float4(acc[i][0] + bv.x, acc[i][1] + bv.y,
                                acc[i][2] + bv.z, acc[i][3] + bv.w);
        *(float4*)&hn[(size_t)n * HH + tx * 4] = o4;
    }
}

// ---------------- layer-2 weights (out=1) ----------------
__global__ void k_makeW2(const float* __restrict__ bases2, const float* __restrict__ comp2,
                         const float* __restrict__ root2, float* __restrict__ W2) {
    int idx = blockIdx.x * blockDim.x + threadIdx.x;
    if (idx >= 6 * HH) return;
    int c = idx >> 6, k = idx & 63;
    float w = (c < RR) ? (comp2[c * NBB + 0] * bases2[k] + comp2[c * NBB + 1] * bases2[HH + k])
                       : root2[k];
    W2[c * HH + k] = w;
}

// ---------------- layer-2 GEMV: xW2[n][r], h2 = root part + bias ----------------
__global__ void k_gemm2(const float* __restrict__ h, const float* __restrict__ W2,
                        const float* __restrict__ bias2, float* __restrict__ xW2,
                        float* __restrict__ h2) {
    int n = blockIdx.x * blockDim.x + threadIdx.x;
    if (n >= NN) return;
    float hr[64];
#pragma unroll
    for (int q = 0; q < 16; q++) {
        float4 v = *(const float4*)&h[(size_t)n * HH + q * 4];
        hr[q * 4 + 0] = v.x; hr[q * 4 + 1] = v.y; hr[q * 4 + 2] = v.z; hr[q * 4 + 3] = v.w;
    }
#pragma unroll
    for (int c = 0; c < 6; c++) {
        float acc = 0.f;
#pragma unroll
        for (int k = 0; k < 64; k++) acc += hr[k] * W2[c * HH + k];
        if (c < RR) xW2[n * RR + c] = acc;
        else        h2[n] = acc + bias2[0];
    }
}

// ---------------- layer-2 gather: thread per dst ----------------
__global__ void k_gather2(const int* __restrict__ rowstart, const int2* __restrict__ epair,
                          const float* __restrict__ xW2, float* __restrict__ h2) {
    int n = blockIdx.x * blockDim.x + threadIdx.x;
    if (n >= NN) return;
    int beg = rowstart[n], end = rowstart[n + 1];
    float acc = h2[n];
    for (int j = beg; j < end; ++j) {
        int2 p = epair[j];
        acc += __int_as_float(p.y) * xW2[(p.x >> 3) * RR + (p.x & 7)];
    }
    h2[n] = acc;
}

// ---------------- masked exp-sum ----------------
__global__ void k_reduce(const float* __restrict__ h2, const int* __restrict__ absorbed,
                         float* __restrict__ denom) {
    __shared__ float sdata[256];
    int tid = threadIdx.x;
    float local = 0.f;
    for (int n = blockIdx.x * 256 + tid; n < NN; n += gridDim.x * 256)
        if (!absorbed[n]) local += expf(h2[n]);
    sdata[tid] = local;
    __syncthreads();
    for (int s = 128; s > 0; s >>= 1) {
        if (tid < s) sdata[tid] += sdata[tid + s];
        __syncthreads();
    }
    if (tid == 0) atomicAdd(denom, sdata[0]);
}

// ---------------- final normalize ----------------
__global__ void k_final(const float* __restrict__ h2, const int* __restrict__ absorbed,
                        const float* __restrict__ denom, float* __restrict__ out) {
    int n = blockIdx.x * blockDim.x + threadIdx.x;
    if (n >= NN) return;
    out[n] = absorbed[n] ? 0.f : expf(h2[n]) / denom[0];
}

extern "C" void kernel_launch(void* const* d_in, const int* in_sizes, int n_in,
                              void* d_out, int out_size, void* d_ws, size_t ws_size,
                              hipStream_t stream) {
    const int* x     = (const int*)d_in[0];
    const int* ei    = (const int*)d_in[1];
    const int* et    = (const int*)d_in[2];
    const int* order = (const int*)d_in[3];
    const float* emb = (const float*)d_in[4];
    const float* bases[3] = {(const float*)d_in[5], (const float*)d_in[9],  (const float*)d_in[13]};
    const float* comp[3]  = {(const float*)d_in[6], (const float*)d_in[10], (const float*)d_in[14]};
    const float* root[3]  = {(const float*)d_in[7], (const float*)d_in[11], (const float*)d_in[15]};
    const float* bias[3]  = {(const float*)d_in[8], (const float*)d_in[12], (const float*)d_in[16]};
    const int* srcp = ei;
    const int* dstp = ei + NE;

    char* w = (char*)d_ws;
    size_t off = 0;
    auto alloc = [&](size_t bytes) -> void* {
        void* p = w + off;
        off = (off + bytes + 255) & ~(size_t)255;
        return p;
    };
    float* h        = (float*)alloc((size_t)NN * HH * 4);
    float* hn       = (float*)alloc((size_t)NN * HH * 4);
    float* mixbuf   = (float*)alloc((size_t)NN * 128 * 4);
    float* xW2      = (float*)alloc((size_t)NN * RR * 4);
    float* h2       = (float*)alloc((size_t)NN * 4);
    int*   cnt      = (int*)alloc((size_t)NN * RR * 4);
    int*   absorbed = (int*)alloc((size_t)NN * 4);
    int*   rowstart = (int*)alloc((size_t)(NN + 1) * 4);
    int*   cursor   = (int*)alloc((size_t)NN * 4);
    int*   bsum     = (int*)alloc((size_t)NBLK * 4);
    int2*  epair    = (int2*)alloc((size_t)NE * 8);
    float* W2       = (float*)alloc((size_t)6 * HH * 4);
    float* denom    = (float*)alloc(256);

    hipMemsetAsync(cnt, 0, (size_t)NN * RR * 4, stream);
    hipMemsetAsync(cursor, 0, (size_t)NN * 4, stream);
    hipMemsetAsync(absorbed, 0, (size_t)NN * 4, stream);
    hipMemsetAsync(denom, 0, 4, stream);

    k_init_h<<<(NN * 16 + 255) / 256, 256, 0, stream>>>(x, (const float4*)emb, (float4*)h);
    k_pe<<<(KK * 16 + 255) / 256, 256, 0, stream>>>(order, h, absorbed);
    k_cnt<<<(NE + 255) / 256, 256, 0, stream>>>(dstp, et, cnt);

    // CSR build
    k_scan1<<<NBLK, 256, 0, stream>>>(cnt, rowstart, bsum);
    k_scan2<<<1, 512, 0, stream>>>(bsum);
    k_scan3<<<NBLK, 256, 0, stream>>>(rowstart, bsum);
    k_place<<<(NE + 255) / 256, 256, 0, stream>>>(srcp, dstp, et, cnt, rowstart, cursor, epair);

    int gmix = (NN * 64 + 255) / 256;
    int ggemm = (NN + 63) / 64;

    // layer 0: h -> hn
    k_gather_mix<<<gmix, 256, 0, stream>>>(rowstart, epair, comp[0], h, mixbuf);
    k_gemmL<<<ggemm, 256, 0, stream>>>(mixbuf, h, bases[0], root[0], bias[0], hn);

    // layer 1: hn -> h
    k_gather_mix<<<gmix, 256, 0, stream>>>(rowstart, epair, comp[1], hn, mixbuf);
    k_gemmL<<<ggemm, 256, 0, stream>>>(mixbuf, hn, bases[1], root[1], bias[1], h);

    // layer 2: h -> h2
    k_makeW2<<<2, 256, 0, stream>>>(bases[2], comp[2], root[2], W2);
    k_gemm2<<<(NN + 255) / 256, 256, 0, stream>>>(h, W2, bias[2], xW2, h2);
    k_gather2<<<(NN + 255) / 256, 256, 0, stream>>>(rowstart, epair, xW2, h2);

    k_reduce<<<256, 256, 0, stream>>>(h2, absorbed, denom);
    k_final<<<(NN + 255) / 256, 256, 0, stream>>>(h2, absorbed, denom, (float*)d_out);
}

// Round 5
// 340.525 us; speedup vs baseline: 9.0965x; 1.2715x over previous
//
#include <hip/hip_runtime.h>
#include <math.h>

#define NN 100000
#define NE 1600000
#define RR 5
#define HH 64
#define KK 10000
#define NBB 2
#define NBK 391            // dst buckets of 256 nodes: ceil(100000/256)
#define EPB 6250           // edges per block in bucket passes (256 blocks)
#define BCAP 8192          // pass-2 LDS capacity per bucket (mean 4096, std 64)

// ---------------- h init: h[n] = emb[x[n]] ----------------
__global__ void k_init_h(const int* __restrict__ x, const float4* __restrict__ emb4,
                         float4* __restrict__ h4) {
    int idx = blockIdx.x * blockDim.x + threadIdx.x;
    if (idx >= NN * 16) return;
    int n = idx >> 4;
    int q = idx & 15;
    h4[idx] = emb4[x[n] * 16 + q];
}

// ---------------- PE add + absorbed mask (node_order entries distinct) ----------------
__global__ void k_pe(const int* __restrict__ order, float* __restrict__ h,
                     int* __restrict__ absorbed) {
    int idx = blockIdx.x * blockDim.x + threadIdx.x;
    if (idx >= KK * 16) return;
    int t = idx >> 4;
    int q = idx & 15;
    int node = order[t];
    float v = (float)sin((double)(t + 1));   // exact arg reduction, matches np
    float* p = h + (size_t)node * HH + q * 4;
    p[0] += v; p[1] += v; p[2] += v; p[3] += v;
    if (q == 0) absorbed[node] = 1;
}

// ---------------- bucket pass 1a: per-block LDS histogram over dst>>8 ----------------
__global__ void k_bcnt(const int* __restrict__ dst, int* __restrict__ gbcnt) {
    __shared__ int hist[NBK];
    int tid = threadIdx.x;
    for (int i = tid; i < NBK; i += 256) hist[i] = 0;
    __syncthreads();
    int e0 = blockIdx.x * EPB;
    int e1 = e0 + EPB < NE ? e0 + EPB : NE;
    for (int e = e0 + tid; e < e1; e += 256)
        atomicAdd(&hist[dst[e] >> 8], 1);
    __syncthreads();
    for (int i = tid; i < NBK; i += 256)
        if (hist[i]) atomicAdd(&gbcnt[i], hist[i]);
}

// ---------------- bucket pass 1b: exclusive scan of 391 bucket sizes ----------------
__global__ void k_bscan(const int* __restrict__ gbcnt, int* __restrict__ bbase) {
    __shared__ int s[512];
    int tid = threadIdx.x;
    int v = (tid < NBK) ? gbcnt[tid] : 0;
    s[tid] = v;
    __syncthreads();
#pragma unroll
    for (int off = 1; off < 512; off <<= 1) {
        int t = (tid >= off) ? s[tid - off] : 0;
        __syncthreads();
        s[tid] += t;
        __syncthreads();
    }
    if (tid < NBK) bbase[tid] = s[tid] - v;
    if (tid == NBK - 1) bbase[NBK] = s[tid];
}

// ---------------- bucket pass 1c: block-span reservation + packed scatter ----------------
// entry = (dst&255)<<20 | src<<3 | rel   (src<2^17, rel<2^3)
__global__ void k_bplace(const int* __restrict__ src, const int* __restrict__ dst,
                         const int* __restrict__ et, const int* __restrict__ bbase,
                         int* __restrict__ bcur, unsigned int* __restrict__ ebuf) {
    __shared__ int hist[NBK];
    __shared__ int lbase[NBK];
    __shared__ int lcur[NBK];
    int tid = threadIdx.x;
    for (int i = tid; i < NBK; i += 256) { hist[i] = 0; lcur[i] = 0; }
    __syncthreads();
    int e0 = blockIdx.x * EPB;
    int e1 = e0 + EPB < NE ? e0 + EPB : NE;
    for (int e = e0 + tid; e < e1; e += 256)
        atomicAdd(&hist[dst[e] >> 8], 1);
    __syncthreads();
    for (int i = tid; i < NBK; i += 256)
        if (hist[i]) lbase[i] = bbase[i] + atomicAdd(&bcur[i], hist[i]);
    __syncthreads();
    for (int e = e0 + tid; e < e1; e += 256) {
        int d = dst[e];
        int b = d >> 8;
        int r = atomicAdd(&lcur[b], 1);
        ebuf[lbase[b] + r] = ((unsigned)(d & 255) << 20) | ((unsigned)src[e] << 3) | (unsigned)et[e];
    }
}

// ---------------- bucket pass 2: per-bucket exact sort + norm + rowstart + epair ----------------
__launch_bounds__(256)
__global__ void k_bsort(const unsigned int* __restrict__ ebuf, const int* __restrict__ bbase,
                        int2* __restrict__ epair, int* __restrict__ rowstart) {
    __shared__ unsigned int el[BCAP];
    __shared__ int cnt5[256 * RR];
    __shared__ float norm5[256 * RR];
    __shared__ int dcur[256];
    __shared__ int s[256];
    int tid = threadIdx.x;
    int b = blockIdx.x;
    int base = bbase[b];
    int sz = bbase[b + 1] - base;
    if (sz > BCAP) sz = BCAP;   // statistically impossible; prevents corruption

    for (int i = tid; i < sz; i += 256) el[i] = ebuf[base + i];
    for (int i = tid; i < 256 * RR; i += 256) cnt5[i] = 0;
    __syncthreads();
    for (int i = tid; i < sz; i += 256) {
        unsigned int e = el[i];
        atomicAdd(&cnt5[(e >> 20) * RR + (e & 7)], 1);
    }
    __syncthreads();
    // per-dst degree + block scan (exclusive)
    int deg = 0;
#pragma unroll
    for (int r = 0; r < RR; r++) deg += cnt5[tid * RR + r];
    s[tid] = deg;
    dcur[tid] = 0;
    __syncthreads();
#pragma unroll
    for (int off = 1; off < 256; off <<= 1) {
        int t = (tid >= off) ? s[tid - off] : 0;
        __syncthreads();
        s[tid] += t;
        __syncthreads();
    }
    int rs = s[tid] - deg;      // exclusive scan
    for (int i = tid; i < 256 * RR; i += 256) {
        int c = cnt5[i];
        norm5[i] = 1.0f / (float)(c > 1 ? c : 1);
    }
    __syncthreads();
    // placement into global epair (one CU -> L2-local writes)
    for (int i = tid; i < sz; i += 256) {
        unsigned int e = el[i];
        int d8 = e >> 20;
        int rk = atomicAdd(&dcur[d8], 1);
        // reconstruct this dst's exclusive base from scan: need s[]-based value of lane d8
        // stored per-thread; use shared rs via s[]: s[] currently holds inclusive sums.
        int pos = base + (s[d8] - (cnt5[d8 * RR + 0] + cnt5[d8 * RR + 1] + cnt5[d8 * RR + 2]
                                   + cnt5[d8 * RR + 3] + cnt5[d8 * RR + 4])) + rk;
        epair[pos] = make_int2((int)(e & 0xFFFFFu), __float_as_int(norm5[d8 * RR + (e & 7)]));
    }
    // rowstart
    int d = b * 256 + tid;
    if (d < NN) rowstart[d] = base + rs;
    if (b == 0 && tid == 0) rowstart[NN] = NE;
}

// ---------------- basis-mixed gather: wave per dst, 4 edge-groups x float4 lanes ----------------
__launch_bounds__(256)
__global__ void k_gather_mix(const int* __restrict__ rowstart, const int2* __restrict__ epair,
                             const float* __restrict__ comp, const float* __restrict__ h,
                             float* __restrict__ mixbuf) {
    __shared__ float2 lut[8];
    if (threadIdx.x < 8) {
        int r = threadIdx.x < RR ? threadIdx.x : 0;
        lut[threadIdx.x] = make_float2(comp[r * NBB + 0], comp[r * NBB + 1]);
    }
    __syncthreads();
    int wid = (blockIdx.x * blockDim.x + threadIdx.x) >> 6;
    if (wid >= NN) return;
    int lane = threadIdx.x & 63;
    int eg = lane >> 4;          // edge group 0..3
    int dq = lane & 15;          // dim quarter: dims [dq*4, dq*4+4)
    int beg = rowstart[wid], end = rowstart[wid + 1];

    float4 m0 = make_float4(0.f, 0.f, 0.f, 0.f);
    float4 m1 = make_float4(0.f, 0.f, 0.f, 0.f);

    for (int j = beg; j < end; j += 8) {
        int jj0 = j + eg;
        int jj1 = j + 4 + eg;
        int2 pa = (jj0 < end) ? epair[jj0] : make_int2(0, 0);
        int2 pb = (jj1 < end) ? epair[jj1] : make_int2(0, 0);
        float4 ha = *(const float4*)&h[(size_t)(pa.x >> 3) * HH + dq * 4];
        float4 hb = *(const float4*)&h[(size_t)(pb.x >> 3) * HH + dq * 4];
        float2 ca = lut[pa.x & 7];
        float2 cb = lut[pb.x & 7];
        float na = __int_as_float(pa.y);
        float nb = __int_as_float(pb.y);
        float a0 = ca.x * na, a1 = ca.y * na;
        float b0 = cb.x * nb, b1 = cb.y * nb;
        m0.x += a0 * ha.x; m0.y += a0 * ha.y; m0.z += a0 * ha.z; m0.w += a0 * ha.w;
        m1.x += a1 * ha.x; m1.y += a1 * ha.y; m1.z += a1 * ha.z; m1.w += a1 * ha.w;
        m0.x += b0 * hb.x; m0.y += b0 * hb.y; m0.z += b0 * hb.z; m0.w += b0 * hb.w;
        m1.x += b1 * hb.x; m1.y += b1 * hb.y; m1.z += b1 * hb.z; m1.w += b1 * hb.w;
    }

    // fold the 4 edge groups: butterfly over lane bits 4,5
#pragma unroll
    for (int off = 16; off < 64; off <<= 1) {
        m0.x += __shfl_xor(m0.x, off); m0.y += __shfl_xor(m0.y, off);
        m0.z += __shfl_xor(m0.z, off); m0.w += __shfl_xor(m0.w, off);
        m1.x += __shfl_xor(m1.x, off); m1.y += __shfl_xor(m1.y, off);
        m1.z += __shfl_xor(m1.z, off); m1.w += __shfl_xor(m1.w, off);
    }

    if (eg == 0)      *(float4*)&mixbuf[(size_t)wid * 128 + dq * 4]      = m0;
    else if (eg == 1) *(float4*)&mixbuf[(size_t)wid * 128 + 64 + dq * 4] = m1;
}

// ---------------- layer GEMM: hn = [mix0|mix1|h] (K=192) x [B0;B1;root] + bias ----------------
__launch_bounds__(256)
__global__ void k_gemmL(const float* __restrict__ mixbuf, const float* __restrict__ h,
                        const float* __restrict__ bases, const float* __restrict__ root,
                        const float* __restrict__ bias, float* __restrict__ hn) {
    __shared__ float hsT[64][68];  // [k][node]
    __shared__ float ws[64][68];   // [k][o]
    int tid = threadIdx.x;
    int n0 = blockIdx.x * 64;
    int tx = tid & 15, ty = tid >> 4;
    float acc[4][4];
#pragma unroll
    for (int i = 0; i < 4; i++)
#pragma unroll
        for (int j = 0; j < 4; j++) acc[i][j] = 0.f;

    for (int chunk = 0; chunk < 3; ++chunk) {
        __syncthreads();
        for (int i = tid; i < 64 * 16; i += 256) {
            int row = i >> 4;            // A: node idx | W: k idx
            int q4 = (i & 15) * 4;       // A: k offset | W: o offset
            int n = n0 + row;
            float4 v = make_float4(0.f, 0.f, 0.f, 0.f);
            if (n < NN) {
                const float* asrc = (chunk == 0) ? &mixbuf[(size_t)n * 128 + q4]
                                  : (chunk == 1) ? &mixbuf[(size_t)n * 128 + 64 + q4]
                                                 : &h[(size_t)n * HH + q4];
                v = *(const float4*)asrc;
            }
            hsT[q4 + 0][row] = v.x; hsT[q4 + 1][row] = v.y;
            hsT[q4 + 2][row] = v.z; hsT[q4 + 3][row] = v.w;

            const float* wsrc = (chunk == 0) ? &bases[(size_t)row * HH + q4]
                              : (chunk == 1) ? &bases[(size_t)(64 + row) * HH + q4]
                                             : &root[(size_t)row * HH + q4];
            *(float4*)&ws[row][q4] = *(const float4*)wsrc;
        }
        __syncthreads();

#pragma unroll
        for (int k = 0; k < 64; ++k) {
            float4 a4 = *(const float4*)&hsT[k][ty * 4];
            float4 b4 = *(const float4*)&ws[k][tx * 4];
            float a[4] = {a4.x, a4.y, a4.z, a4.w};
            float b[4] = {b4.x, b4.y, b4.z, b4.w};
#pragma unroll
            for (int i = 0; i < 4; i++)
#pragma unroll
                for (int j = 0; j < 4; j++) acc[i][j] += a[i] * b[j];
        }
    }

    float4 bv = *(const float4*)&bias[tx * 4];
#pragma unroll
    for (int i = 0; i < 4; i++) {
        int n = n0 + ty * 4 + i;
        if (n >= NN) continue;
        float4 o4 = make_float4(acc[i][0] + bv.x, acc[i][1] + bv.y,
                                acc[i][2] + bv.z, acc[i][3] + bv.w);
        *(float4*)&hn[(size_t)n * HH + tx * 4] = o4;
    }
}

// ---------------- layer-2 weights (out=1) ----------------
__global__ void k_makeW2(const float* __restrict__ bases2, const float* __restrict__ comp2,
                         const float* __restrict__ root2, float* __restrict__ W2) {
    int idx = blockIdx.x * blockDim.x + threadIdx.x;
    if (idx >= 6 * HH) return;
    int c = idx >> 6, k = idx & 63;
    float w = (c < RR) ? (comp2[c * NBB + 0] * bases2[k] + comp2[c * NBB + 1] * bases2[HH + k])
                       : root2[k];
    W2[c * HH + k] = w;
}

// ---------------- layer-2 GEMV: xW2[n][r], h2 = root part + bias ----------------
__global__ void k_gemm2(const float* __restrict__ h, const float* __restrict__ W2,
                        const float* __restrict__ bias2, float* __restrict__ xW2,
                        float* __restrict__ h2) {
    int n = blockIdx.x * blockDim.x + threadIdx.x;
    if (n >= NN) return;
    float hr[64];
#pragma unroll
    for (int q = 0; q < 16; q++) {
        float4 v = *(const float4*)&h[(size_t)n * HH + q * 4];
        hr[q * 4 + 0] = v.x; hr[q * 4 + 1] = v.y; hr[q * 4 + 2] = v.z; hr[q * 4 + 3] = v.w;
    }
#pragma unroll
    for (int c = 0; c < 6; c++) {
        float acc = 0.f;
#pragma unroll
        for (int k = 0; k < 64; k++) acc += hr[k] * W2[c * HH + k];
        if (c < RR) xW2[n * RR + c] = acc;
        else        h2[n] = acc + bias2[0];
    }
}

// ---------------- layer-2 gather: thread per dst ----------------
__global__ void k_gather2(const int* __restrict__ rowstart, const int2* __restrict__ epair,
                          const float* __restrict__ xW2, float* __restrict__ h2) {
    int n = blockIdx.x * blockDim.x + threadIdx.x;
    if (n >= NN) return;
    int beg = rowstart[n], end = rowstart[n + 1];
    float acc = h2[n];
    for (int j = beg; j < end; ++j) {
        int2 p = epair[j];
        acc += __int_as_float(p.y) * xW2[(p.x >> 3) * RR + (p.x & 7)];
    }
    h2[n] = acc;
}

// ---------------- masked exp-sum ----------------
__global__ void k_reduce(const float* __restrict__ h2, const int* __restrict__ absorbed,
                         float* __restrict__ denom) {
    __shared__ float sdata[256];
    int tid = threadIdx.x;
    float local = 0.f;
    for (int n = blockIdx.x * 256 + tid; n < NN; n += gridDim.x * 256)
        if (!absorbed[n]) local += expf(h2[n]);
    sdata[tid] = local;
    __syncthreads();
    for (int s = 128; s > 0; s >>= 1) {
        if (tid < s) sdata[tid] += sdata[tid + s];
        __syncthreads();
    }
    if (tid == 0) atomicAdd(denom, sdata[0]);
}

// ---------------- final normalize ----------------
__global__ void k_final(const float* __restrict__ h2, const int* __restrict__ absorbed,
                        const float* __restrict__ denom, float* __restrict__ out) {
    int n = blockIdx.x * blockDim.x + threadIdx.x;
    if (n >= NN) return;
    out[n] = absorbed[n] ? 0.f : expf(h2[n]) / denom[0];
}

extern "C" void kernel_launch(void* const* d_in, const int* in_sizes, int n_in,
                              void* d_out, int out_size, void* d_ws, size_t ws_size,
                              hipStream_t stream) {
    const int* x     = (const int*)d_in[0];
    const int* ei    = (const int*)d_in[1];
    const int* et    = (const int*)d_in[2];
    const int* order = (const int*)d_in[3];
    const float* emb = (const float*)d_in[4];
    const float* bases[3] = {(const float*)d_in[5], (const float*)d_in[9],  (const float*)d_in[13]};
    const float* comp[3]  = {(const float*)d_in[6], (const float*)d_in[10], (const float*)d_in[14]};
    const float* root[3]  = {(const float*)d_in[7], (const float*)d_in[11], (const float*)d_in[15]};
    const float* bias[3]  = {(const float*)d_in[8], (const float*)d_in[12], (const float*)d_in[16]};
    const int* srcp = ei;
    const int* dstp = ei + NE;

    char* w = (char*)d_ws;
    size_t off = 0;
    auto alloc = [&](size_t bytes) -> void* {
        void* p = w + off;
        off = (off + bytes + 255) & ~(size_t)255;
        return p;
    };
    float* h        = (float*)alloc((size_t)NN * HH * 4);
    float* hn       = (float*)alloc((size_t)NN * HH * 4);
    float* mixbuf   = (float*)alloc((size_t)NN * 128 * 4);
    float* xW2      = (float*)alloc((size_t)NN * RR * 4);
    float* h2       = (float*)alloc((size_t)NN * 4);
    int*   absorbed = (int*)alloc((size_t)NN * 4);
    int*   rowstart = (int*)alloc((size_t)(NN + 1) * 4);
    int*   gbcnt    = (int*)alloc((size_t)NBK * 4);
    int*   bcur     = (int*)alloc((size_t)NBK * 4);
    int*   bbase    = (int*)alloc((size_t)(NBK + 1) * 4);
    unsigned int* ebuf = (unsigned int*)alloc((size_t)NE * 4);
    int2*  epair    = (int2*)alloc((size_t)NE * 8);
    float* W2       = (float*)alloc((size_t)6 * HH * 4);
    float* denom    = (float*)alloc(256);

    hipMemsetAsync(gbcnt, 0, (size_t)NBK * 4, stream);
    hipMemsetAsync(bcur, 0, (size_t)NBK * 4, stream);
    hipMemsetAsync(absorbed, 0, (size_t)NN * 4, stream);
    hipMemsetAsync(denom, 0, 4, stream);

    k_init_h<<<(NN * 16 + 255) / 256, 256, 0, stream>>>(x, (const float4*)emb, (float4*)h);
    k_pe<<<(KK * 16 + 255) / 256, 256, 0, stream>>>(order, h, absorbed);

    // bucketed CSR build
    k_bcnt<<<256, 256, 0, stream>>>(dstp, gbcnt);
    k_bscan<<<1, 512, 0, stream>>>(gbcnt, bbase);
    k_bplace<<<256, 256, 0, stream>>>(srcp, dstp, et, bbase, bcur, ebuf);
    k_bsort<<<NBK, 256, 0, stream>>>(ebuf, bbase, epair, rowstart);

    int gmix = (NN * 64 + 255) / 256;
    int ggemm = (NN + 63) / 64;

    // layer 0: h -> hn
    k_gather_mix<<<gmix, 256, 0, stream>>>(rowstart, epair, comp[0], h, mixbuf);
    k_gemmL<<<ggemm, 256, 0, stream>>>(mixbuf, h, bases[0], root[0], bias[0], hn);

    // layer 1: hn -> h
    k_gather_mix<<<gmix, 256, 0, stream>>>(rowstart, epair, comp[1], hn, mixbuf);
    k_gemmL<<<ggemm, 256, 0, stream>>>(mixbuf, hn, bases[1], root[1], bias[1], h);

    // layer 2: h -> h2
    k_makeW2<<<2, 256, 0, stream>>>(bases[2], comp[2], root[2], W2);
    k_gemm2<<<(NN + 255) / 256, 256, 0, stream>>>(h, W2, bias[2], xW2, h2);
    k_gather2<<<(NN + 255) / 256, 256, 0, stream>>>(rowstart, epair, xW2, h2);

    k_reduce<<<256, 256, 0, stream>>>(h2, absorbed, denom);
    k_final<<<(NN + 255) / 256, 256, 0, stream>>>(h2, absorbed, denom, (float*)d_out);
}

// Round 6
// 301.982 us; speedup vs baseline: 10.2575x; 1.1276x over previous
//
#include <hip/hip_runtime.h>
#include <hip/hip_fp16.h>
#include <math.h>

#define NN 100000
#define NE 1600000
#define RR 5
#define HH 64
#define KK 10000
#define NBB 2
#define NBK 391            // dst buckets of 256 nodes: ceil(100000/256)
#define EPB 6250           // edges per block in bucket passes (256 blocks)
#define BCAP 8192          // pass-2 LDS capacity per bucket (mean 4096, std 64)

// ---------------- h init: h[n] = emb[x[n]] (fp32 + fp16 mirror) + zero scratch ----------------
__global__ void k_init_h(const int* __restrict__ x, const float4* __restrict__ emb4,
                         float4* __restrict__ h4, unsigned short* __restrict__ hH,
                         int* __restrict__ gbcnt, int* __restrict__ bcur,
                         int* __restrict__ absorbed, float* __restrict__ denom) {
    int idx = blockIdx.x * blockDim.x + threadIdx.x;
    if (idx >= NN * 16) return;
    int n = idx >> 4;
    int q = idx & 15;
    float4 v = emb4[x[n] * 16 + q];
    h4[idx] = v;
    __half2 lo = __floats2half2_rn(v.x, v.y);
    __half2 hi = __floats2half2_rn(v.z, v.w);
    *(uint2*)&hH[(size_t)n * HH + q * 4] = make_uint2(*(unsigned*)&lo, *(unsigned*)&hi);
    // fold in scratch zeroing (completes before dependent kernels by stream order)
    if (idx < NBK) { gbcnt[idx] = 0; bcur[idx] = 0; }
    if (idx == NBK) denom[0] = 0.f;
    if (idx < NN) absorbed[idx] = 0;
}

// ---------------- PE add + absorbed mask (node_order entries distinct) ----------------
__global__ void k_pe(const int* __restrict__ order, float* __restrict__ h,
                     unsigned short* __restrict__ hH, int* __restrict__ absorbed) {
    int idx = blockIdx.x * blockDim.x + threadIdx.x;
    if (idx >= KK * 16) return;
    int t = idx >> 4;
    int q = idx & 15;
    int node = order[t];
    float v = (float)sin((double)(t + 1));   // exact arg reduction, matches np
    float* p = h + (size_t)node * HH + q * 4;
    float a = p[0] + v, b = p[1] + v, c = p[2] + v, d = p[3] + v;
    p[0] = a; p[1] = b; p[2] = c; p[3] = d;
    __half2 lo = __floats2half2_rn(a, b);
    __half2 hi = __floats2half2_rn(c, d);
    *(uint2*)&hH[(size_t)node * HH + q * 4] = make_uint2(*(unsigned*)&lo, *(unsigned*)&hi);
    if (q == 0) absorbed[node] = 1;
}

// ---------------- bucket pass 1a: per-block LDS histogram over dst>>8 ----------------
__global__ void k_bcnt(const int* __restrict__ dst, int* __restrict__ gbcnt) {
    __shared__ int hist[NBK];
    int tid = threadIdx.x;
    for (int i = tid; i < NBK; i += 256) hist[i] = 0;
    __syncthreads();
    int e0 = blockIdx.x * EPB;
    int e1 = e0 + EPB < NE ? e0 + EPB : NE;
    for (int e = e0 + tid; e < e1; e += 256)
        atomicAdd(&hist[dst[e] >> 8], 1);
    __syncthreads();
    for (int i = tid; i < NBK; i += 256)
        if (hist[i]) atomicAdd(&gbcnt[i], hist[i]);
}

// ---------------- bucket pass 1b: exclusive scan of 391 bucket sizes ----------------
__global__ void k_bscan(const int* __restrict__ gbcnt, int* __restrict__ bbase) {
    __shared__ int s[512];
    int tid = threadIdx.x;
    int v = (tid < NBK) ? gbcnt[tid] : 0;
    s[tid] = v;
    __syncthreads();
#pragma unroll
    for (int off = 1; off < 512; off <<= 1) {
        int t = (tid >= off) ? s[tid - off] : 0;
        __syncthreads();
        s[tid] += t;
        __syncthreads();
    }
    if (tid < NBK) bbase[tid] = s[tid] - v;
    if (tid == NBK - 1) bbase[NBK] = s[tid];
}

// ---------------- bucket pass 1c: block-span reservation + packed scatter ----------------
// entry = (dst&255)<<20 | src<<3 | rel   (src<2^17, rel<2^3)
__global__ void k_bplace(const int* __restrict__ src, const int* __restrict__ dst,
                         const int* __restrict__ et, const int* __restrict__ bbase,
                         int* __restrict__ bcur, unsigned int* __restrict__ ebuf) {
    __shared__ int hist[NBK];
    __shared__ int lbase[NBK];
    __shared__ int lcur[NBK];
    int tid = threadIdx.x;
    for (int i = tid; i < NBK; i += 256) { hist[i] = 0; lcur[i] = 0; }
    __syncthreads();
    int e0 = blockIdx.x * EPB;
    int e1 = e0 + EPB < NE ? e0 + EPB : NE;
    for (int e = e0 + tid; e < e1; e += 256)
        atomicAdd(&hist[dst[e] >> 8], 1);
    __syncthreads();
    for (int i = tid; i < NBK; i += 256)
        if (hist[i]) lbase[i] = bbase[i] + atomicAdd(&bcur[i], hist[i]);
    __syncthreads();
    for (int e = e0 + tid; e < e1; e += 256) {
        int d = dst[e];
        int b = d >> 8;
        int r = atomicAdd(&lcur[b], 1);
        ebuf[lbase[b] + r] = ((unsigned)(d & 255) << 20) | ((unsigned)src[e] << 3) | (unsigned)et[e];
    }
}

// ---------------- bucket pass 2: per-bucket exact sort + norm + rowstart + epair ----------------
__launch_bounds__(256)
__global__ void k_bsort(const unsigned int* __restrict__ ebuf, const int* __restrict__ bbase,
                        int2* __restrict__ epair, int* __restrict__ rowstart) {
    __shared__ unsigned int el[BCAP];
    __shared__ int cnt5[256 * RR];
    __shared__ float norm5[256 * RR];
    __shared__ int dcur[256];
    __shared__ int s[256];
    int tid = threadIdx.x;
    int b = blockIdx.x;
    int base = bbase[b];
    int sz = bbase[b + 1] - base;
    if (sz > BCAP) sz = BCAP;   // statistically impossible; prevents corruption

    for (int i = tid; i < sz; i += 256) el[i] = ebuf[base + i];
    for (int i = tid; i < 256 * RR; i += 256) cnt5[i] = 0;
    __syncthreads();
    for (int i = tid; i < sz; i += 256) {
        unsigned int e = el[i];
        atomicAdd(&cnt5[(e >> 20) * RR + (e & 7)], 1);
    }
    __syncthreads();
    // per-dst degree + block scan (exclusive)
    int deg = 0;
#pragma unroll
    for (int r = 0; r < RR; r++) deg += cnt5[tid * RR + r];
    s[tid] = deg;
    dcur[tid] = 0;
    __syncthreads();
#pragma unroll
    for (int off = 1; off < 256; off <<= 1) {
        int t = (tid >= off) ? s[tid - off] : 0;
        __syncthreads();
        s[tid] += t;
        __syncthreads();
    }
    int rs = s[tid] - deg;      // exclusive scan
    for (int i = tid; i < 256 * RR; i += 256) {
        int c = cnt5[i];
        norm5[i] = 1.0f / (float)(c > 1 ? c : 1);
    }
    __syncthreads();
    // placement into global epair (one CU -> L2-local writes)
    for (int i = tid; i < sz; i += 256) {
        unsigned int e = el[i];
        int d8 = e >> 20;
        int rk = atomicAdd(&dcur[d8], 1);
        int pos = base + (s[d8] - (cnt5[d8 * RR + 0] + cnt5[d8 * RR + 1] + cnt5[d8 * RR + 2]
                                   + cnt5[d8 * RR + 3] + cnt5[d8 * RR + 4])) + rk;
        epair[pos] = make_int2((int)(e & 0xFFFFFu), __float_as_int(norm5[d8 * RR + (e & 7)]));
    }
    // rowstart
    int d = b * 256 + tid;
    if (d < NN) rowstart[d] = base + rs;
    if (b == 0 && tid == 0) rowstart[NN] = NE;
}

// ---------------- basis-mixed gather (fp16 h): wave per dst, 4 edge-groups x 4-half lanes ----------------
__launch_bounds__(256)
__global__ void k_gather_mix(const int* __restrict__ rowstart, const int2* __restrict__ epair,
                             const float* __restrict__ comp, const unsigned short* __restrict__ hH,
                             float* __restrict__ mixbuf) {
    __shared__ float2 lut[8];
    if (threadIdx.x < 8) {
        int r = threadIdx.x < RR ? threadIdx.x : 0;
        lut[threadIdx.x] = make_float2(comp[r * NBB + 0], comp[r * NBB + 1]);
    }
    __syncthreads();
    int wid = (blockIdx.x * blockDim.x + threadIdx.x) >> 6;
    if (wid >= NN) return;
    int lane = threadIdx.x & 63;
    int eg = lane >> 4;          // edge group 0..3
    int dq = lane & 15;          // dim quarter: dims [dq*4, dq*4+4)
    int beg = rowstart[wid], end = rowstart[wid + 1];

    float4 m0 = make_float4(0.f, 0.f, 0.f, 0.f);
    float4 m1 = make_float4(0.f, 0.f, 0.f, 0.f);

    for (int j = beg; j < end; j += 8) {
        int jj0 = j + eg;
        int jj1 = j + 4 + eg;
        int2 pa = (jj0 < end) ? epair[jj0] : make_int2(0, 0);
        int2 pb = (jj1 < end) ? epair[jj1] : make_int2(0, 0);
        uint2 ua = *(const uint2*)&hH[(size_t)(pa.x >> 3) * HH + dq * 4];
        uint2 ub = *(const uint2*)&hH[(size_t)(pb.x >> 3) * HH + dq * 4];
        float2 a01 = __half22float2(*(__half2*)&ua.x);
        float2 a23 = __half22float2(*(__half2*)&ua.y);
        float2 b01 = __half22float2(*(__half2*)&ub.x);
        float2 b23 = __half22float2(*(__half2*)&ub.y);
        float2 ca = lut[pa.x & 7];
        float2 cb = lut[pb.x & 7];
        float na = __int_as_float(pa.y);
        float nb = __int_as_float(pb.y);
        float a0 = ca.x * na, a1 = ca.y * na;
        float b0 = cb.x * nb, b1 = cb.y * nb;
        m0.x += a0 * a01.x; m0.y += a0 * a01.y; m0.z += a0 * a23.x; m0.w += a0 * a23.y;
        m1.x += a1 * a01.x; m1.y += a1 * a01.y; m1.z += a1 * a23.x; m1.w += a1 * a23.y;
        m0.x += b0 * b01.x; m0.y += b0 * b01.y; m0.z += b0 * b23.x; m0.w += b0 * b23.y;
        m1.x += b1 * b01.x; m1.y += b1 * b01.y; m1.z += b1 * b23.x; m1.w += b1 * b23.y;
    }

    // fold the 4 edge groups: butterfly over lane bits 4,5
#pragma unroll
    for (int off = 16; off < 64; off <<= 1) {
        m0.x += __shfl_xor(m0.x, off); m0.y += __shfl_xor(m0.y, off);
        m0.z += __shfl_xor(m0.z, off); m0.w += __shfl_xor(m0.w, off);
        m1.x += __shfl_xor(m1.x, off); m1.y += __shfl_xor(m1.y, off);
        m1.z += __shfl_xor(m1.z, off); m1.w += __shfl_xor(m1.w, off);
    }

    if (eg == 0)      *(float4*)&mixbuf[(size_t)wid * 128 + dq * 4]      = m0;
    else if (eg == 1) *(float4*)&mixbuf[(size_t)wid * 128 + 64 + dq * 4] = m1;
}

// ---------------- layer GEMM: hn = [mix0|mix1|h] (K=192) x [B0;B1;root] + bias ----------------
// optionally writes an fp16 mirror of hn (for the next layer's gather)
__launch_bounds__(256)
__global__ void k_gemmL(const float* __restrict__ mixbuf, const float* __restrict__ h,
                        const float* __restrict__ bases, const float* __restrict__ root,
                        const float* __restrict__ bias, float* __restrict__ hn,
                        unsigned short* __restrict__ hnH) {
    __shared__ float hsT[64][68];  // [k][node]
    __shared__ float ws[64][68];   // [k][o]
    int tid = threadIdx.x;
    int n0 = blockIdx.x * 64;
    int tx = tid & 15, ty = tid >> 4;
    float acc[4][4];
#pragma unroll
    for (int i = 0; i < 4; i++)
#pragma unroll
        for (int j = 0; j < 4; j++) acc[i][j] = 0.f;

    for (int chunk = 0; chunk < 3; ++chunk) {
        __syncthreads();
        for (int i = tid; i < 64 * 16; i += 256) {
            int row = i >> 4;            // A: node idx | W: k idx
            int q4 = (i & 15) * 4;       // A: k offset | W: o offset
            int n = n0 + row;
            float4 v = make_float4(0.f, 0.f, 0.f, 0.f);
            if (n < NN) {
                const float* asrc = (chunk == 0) ? &mixbuf[(size_t)n * 128 + q4]
                                  : (chunk == 1) ? &mixbuf[(size_t)n * 128 + 64 + q4]
                                                 : &h[(size_t)n * HH + q4];
                v = *(const float4*)asrc;
            }
            hsT[q4 + 0][row] = v.x; hsT[q4 + 1][row] = v.y;
            hsT[q4 + 2][row] = v.z; hsT[q4 + 3][row] = v.w;

            const float* wsrc = (chunk == 0) ? &bases[(size_t)row * HH + q4]
                              : (chunk == 1) ? &bases[(size_t)(64 + row) * HH + q4]
                                             : &root[(size_t)row * HH + q4];
            *(float4*)&ws[row][q4] = *(const float4*)wsrc;
        }
        __syncthreads();

#pragma unroll
        for (int k = 0; k < 64; ++k) {
            float4 a4 = *(const float4*)&hsT[k][ty * 4];
            float4 b4 = *(const float4*)&ws[k][tx * 4];
            float a[4] = {a4.x, a4.y, a4.z, a4.w};
            float b[4] = {b4.x, b4.y, b4.z, b4.w};
#pragma unroll
            for (int i = 0; i < 4; i++)
#pragma unroll
                for (int j = 0; j < 4; j++) acc[i][j] += a[i] * b[j];
        }
    }

    float4 bv = *(const float4*)&bias[tx * 4];
#pragma unroll
    for (int i = 0; i < 4; i++) {
        int n = n0 + ty * 4 + i;
        if (n >= NN) continue;
        float4 o4 = make_float4(acc[i][0] + bv.x, acc[i][1] + bv.y,
                                acc[i][2] + bv.z, acc[i][3] + bv.w);
        *(float4*)&hn[(size_t)n * HH + tx * 4] = o4;
        if (hnH) {
            __half2 lo = __floats2half2_rn(o4.x, o4.y);
            __half2 hi = __floats2half2_rn(o4.z, o4.w);
            *(uint2*)&hnH[(size_t)n * HH + tx * 4] = make_uint2(*(unsigned*)&lo, *(unsigned*)&hi);
        }
    }
}

// ---------------- layer-2: W2 in LDS + GEMV: xW2[n][r], h2 = root part + bias ----------------
__global__ void k_gemm2(const float* __restrict__ h, const float* __restrict__ bases2,
                        const float* __restrict__ comp2, const float* __restrict__ root2,
                        const float* __restrict__ bias2, float* __restrict__ xW2,
                        float* __restrict__ h2) {
    __shared__ float sW2[6 * HH];
    int tid = threadIdx.x;
    for (int i = tid; i < 6 * HH; i += 256) {
        int c = i >> 6, k = i & 63;
        sW2[i] = (c < RR) ? (comp2[c * NBB + 0] * bases2[k] + comp2[c * NBB + 1] * bases2[HH + k])
                          : root2[k];
    }
    __syncthreads();
    int n = blockIdx.x * blockDim.x + tid;
    if (n >= NN) return;
    float hr[64];
#pragma unroll
    for (int q = 0; q < 16; q++) {
        float4 v = *(const float4*)&h[(size_t)n * HH + q * 4];
        hr[q * 4 + 0] = v.x; hr[q * 4 + 1] = v.y; hr[q * 4 + 2] = v.z; hr[q * 4 + 3] = v.w;
    }
#pragma unroll
    for (int c = 0; c < 6; c++) {
        float acc = 0.f;
#pragma unroll
        for (int k = 0; k < 64; k++) acc += hr[k] * sW2[c * HH + k];
        if (c < RR) xW2[n * RR + c] = acc;
        else        h2[n] = acc + bias2[0];
    }
}

// ---------------- layer-2 gather + fused masked exp-sum ----------------
__global__ void k_gather2(const int* __restrict__ rowstart, const int2* __restrict__ epair,
                          const float* __restrict__ xW2, float* __restrict__ h2,
                          const int* __restrict__ absorbed, float* __restrict__ denom) {
    __shared__ float sdata[256];
    int tid = threadIdx.x;
    int n = blockIdx.x * blockDim.x + tid;
    float local = 0.f;
    if (n < NN) {
        int beg = rowstart[n], end = rowstart[n + 1];
        float acc = h2[n];
        for (int j = beg; j < end; ++j) {
            int2 p = epair[j];
            acc += __int_as_float(p.y) * xW2[(p.x >> 3) * RR + (p.x & 7)];
        }
        h2[n] = acc;
        if (!absorbed[n]) local = expf(acc);
    }
    sdata[tid] = local;
    __syncthreads();
    for (int s = 128; s > 0; s >>= 1) {
        if (tid < s) sdata[tid] += sdata[tid + s];
        __syncthreads();
    }
    if (tid == 0) atomicAdd(denom, sdata[0]);
}

// ---------------- final normalize ----------------
__global__ void k_final(const float* __restrict__ h2, const int* __restrict__ absorbed,
                        const float* __restrict__ denom, float* __restrict__ out) {
    int n = blockIdx.x * blockDim.x + threadIdx.x;
    if (n >= NN) return;
    out[n] = absorbed[n] ? 0.f : expf(h2[n]) / denom[0];
}

extern "C" void kernel_launch(void* const* d_in, const int* in_sizes, int n_in,
                              void* d_out, int out_size, void* d_ws, size_t ws_size,
                              hipStream_t stream) {
    const int* x     = (const int*)d_in[0];
    const int* ei    = (const int*)d_in[1];
    const int* et    = (const int*)d_in[2];
    const int* order = (const int*)d_in[3];
    const float* emb = (const float*)d_in[4];
    const float* bases[3] = {(const float*)d_in[5], (const float*)d_in[9],  (const float*)d_in[13]};
    const float* comp[3]  = {(const float*)d_in[6], (const float*)d_in[10], (const float*)d_in[14]};
    const float* root[3]  = {(const float*)d_in[7], (const float*)d_in[11], (const float*)d_in[15]};
    const float* bias[3]  = {(const float*)d_in[8], (const float*)d_in[12], (const float*)d_in[16]};
    const int* srcp = ei;
    const int* dstp = ei + NE;

    char* w = (char*)d_ws;
    size_t off = 0;
    auto alloc = [&](size_t bytes) -> void* {
        void* p = w + off;
        off = (off + bytes + 255) & ~(size_t)255;
        return p;
    };
    float* h        = (float*)alloc((size_t)NN * HH * 4);
    float* hn       = (float*)alloc((size_t)NN * HH * 4);
    unsigned short* hH = (unsigned short*)alloc((size_t)NN * HH * 2);
    float* mixbuf   = (float*)alloc((size_t)NN * 128 * 4);
    float* xW2      = (float*)alloc((size_t)NN * RR * 4);
    float* h2       = (float*)alloc((size_t)NN * 4);
    int*   absorbed = (int*)alloc((size_t)NN * 4);
    int*   rowstart = (int*)alloc((size_t)(NN + 1) * 4);
    int*   gbcnt    = (int*)alloc((size_t)NBK * 4);
    int*   bcur     = (int*)alloc((size_t)NBK * 4);
    int*   bbase    = (int*)alloc((size_t)(NBK + 1) * 4);
    unsigned int* ebuf = (unsigned int*)alloc((size_t)NE * 4);
    int2*  epair    = (int2*)alloc((size_t)NE * 8);
    float* denom    = (float*)alloc(256);

    // init (also zeroes gbcnt/bcur/absorbed/denom)
    k_init_h<<<(NN * 16 + 255) / 256, 256, 0, stream>>>(x, (const float4*)emb, (float4*)h, hH,
                                                        gbcnt, bcur, absorbed, denom);
    k_pe<<<(KK * 16 + 255) / 256, 256, 0, stream>>>(order, h, hH, absorbed);

    // bucketed CSR build
    k_bcnt<<<256, 256, 0, stream>>>(dstp, gbcnt);
    k_bscan<<<1, 512, 0, stream>>>(gbcnt, bbase);
    k_bplace<<<256, 256, 0, stream>>>(srcp, dstp, et, bbase, bcur, ebuf);
    k_bsort<<<NBK, 256, 0, stream>>>(ebuf, bbase, epair, rowstart);

    int gmix = (NN * 64 + 255) / 256;
    int ggemm = (NN + 63) / 64;

    // layer 0: h -> hn (writes fp16 mirror for next gather)
    k_gather_mix<<<gmix, 256, 0, stream>>>(rowstart, epair, comp[0], hH, mixbuf);
    k_gemmL<<<ggemm, 256, 0, stream>>>(mixbuf, h, bases[0], root[0], bias[0], hn, hH);

    // layer 1: hn -> h (no fp16 mirror needed)
    k_gather_mix<<<gmix, 256, 0, stream>>>(rowstart, epair, comp[1], hH, mixbuf);
    k_gemmL<<<ggemm, 256, 0, stream>>>(mixbuf, hn, bases[1], root[1], bias[1], h, (unsigned short*)nullptr);

    // layer 2: h -> h2 (W2 built in-kernel; gather fused with exp-reduce)
    k_gemm2<<<(NN + 255) / 256, 256, 0, stream>>>(h, bases[2], comp[2], root[2], bias[2], xW2, h2);
    k_gather2<<<(NN + 255) / 256, 256, 0, stream>>>(rowstart, epair, xW2, h2, absorbed, denom);

    k_final<<<(NN + 255) / 256, 256, 0, stream>>>(h2, absorbed, denom, (float*)d_out);
}